// Round 11
// baseline (380.850 us; speedup 1.0000x reference)
//
#include <hip/hip_runtime.h>
#include <cstdint>
#include <cstddef>

// Problem constants (B=8, T=8192, D=256, H=16, K=3, decay=0.9, eps=1e-5)
// I/O dtype: fp32. Internal staging: bf16 (MFMA). ws >= 97.3 MB (confirmed r5).
#define TT 8192
#define BB 8
#define DD 256
#define NTOK (BB * TT)

typedef unsigned short u16;
typedef unsigned int u32;

typedef __attribute__((ext_vector_type(8))) short bf16x8;
typedef __attribute__((ext_vector_type(4))) float f32x4;

__device__ __forceinline__ float bf2f(u16 u) {
    u32 v = ((u32)u) << 16;
    float f;
    __builtin_memcpy(&f, &v, 4);
    return f;
}

__device__ __forceinline__ u16 f2bf(float f) {
    u32 v;
    __builtin_memcpy(&v, &f, 4);
    u32 r = (v + 0x7FFFu + ((v >> 16) & 1u)) >> 16;  // RNE
    return (u16)r;
}

__device__ __forceinline__ uint2 pack4(const float* v) {
    uint2 p;
    p.x = (u32)f2bf(v[0]) | ((u32)f2bf(v[1]) << 16);
    p.y = (u32)f2bf(v[2]) | ((u32)f2bf(v[3]) << 16);
    return p;
}

__device__ __forceinline__ void unpack4(uint2 p, float* v) {
    v[0] = bf2f((u16)(p.x & 0xFFFFu));
    v[1] = bf2f((u16)(p.x >> 16));
    v[2] = bf2f((u16)(p.y & 0xFFFFu));
    v[3] = bf2f((u16)(p.y >> 16));
}

__device__ __forceinline__ uint4 pack8(const float* v) {
    uint4 p;
    p.x = (u32)f2bf(v[0]) | ((u32)f2bf(v[1]) << 16);
    p.y = (u32)f2bf(v[2]) | ((u32)f2bf(v[3]) << 16);
    p.z = (u32)f2bf(v[4]) | ((u32)f2bf(v[5]) << 16);
    p.w = (u32)f2bf(v[6]) | ((u32)f2bf(v[7]) << 16);
    return p;
}

__device__ __forceinline__ void unpack8(uint4 p, float* v) {
    v[0] = bf2f((u16)(p.x & 0xFFFFu));
    v[1] = bf2f((u16)(p.x >> 16));
    v[2] = bf2f((u16)(p.y & 0xFFFFu));
    v[3] = bf2f((u16)(p.y >> 16));
    v[4] = bf2f((u16)(p.z & 0xFFFFu));
    v[5] = bf2f((u16)(p.z >> 16));
    v[6] = bf2f((u16)(p.w & 0xFFFFu));
    v[7] = bf2f((u16)(p.w >> 16));
}

// ---------------------------------------------------------------------------
__global__ __launch_bounds__(256) void k_diag(float* out, float code) {
    out[(size_t)blockIdx.x * 256 + threadIdx.x] = code;
}

// ---------------------------------------------------------------------------
// Weight transpose/convert fp32 -> bf16 (proven) + bias compose folded in
// (z=6,7).
// ---------------------------------------------------------------------------
__global__ __launch_bounds__(256) void k_transpose(
    const float* s0, const float* s1, const float* s2, const float* s3,
    const float* s4, const float* s5,
    u16* d0, u16* d1, u16* d2, u16* d3, u16* d4, u16* d5,
    const float* tbv, const float* tbo, const float* abv, const float* abo,
    float* bc1, float* bc2) {
    const int z = blockIdx.z;
    if (z >= 6) {  // bias compose: bc[n] = sum_j bv[j]*Wo[j][n] + bo[n]
        if (blockIdx.x || blockIdx.y) return;
        const float* bv = (z == 7) ? abv : tbv;
        const float* Wo = (z == 7) ? s1 : s0;  // aWo : tWo (fp32 sources)
        const float* bo = (z == 7) ? abo : tbo;
        float* bc = (z == 7) ? bc2 : bc1;
        const int n = threadIdx.x;
        float s = bo[n];
        for (int j = 0; j < 256; j++) s += bv[j] * Wo[j * 256 + n];
        bc[n] = s;
        return;
    }
    const float* src;
    u16* dst;
    int K, N, tr;
    switch (z) {
        case 0: src = s0; dst = d0; K = 256; N = 256; tr = 1; break;
        case 1: src = s1; dst = d1; K = 256; N = 256; tr = 1; break;
        case 2: src = s2; dst = d2; K = 256; N = 512; tr = 1; break;
        case 3: src = s3; dst = d3; K = 512; N = 256; tr = 1; break;
        case 4: src = s4; dst = d4; K = 256; N = 256; tr = 0; break;
        default: src = s5; dst = d5; K = 256; N = 256; tr = 0; break;
    }
    const int nb = blockIdx.x * 32, kb = blockIdx.y * 32;
    if (nb >= N || kb >= K) return;
    const int tx = threadIdx.x & 31, ty = threadIdx.x >> 5;
    if (!tr) {
        for (int i = ty; i < 32; i += 8)
            dst[(size_t)(kb + i) * N + nb + tx] =
                f2bf(src[(size_t)(kb + i) * N + nb + tx]);
        return;
    }
    __shared__ u16 tile[32][33];
    for (int i = ty; i < 32; i += 8)
        tile[i][tx] = f2bf(src[(size_t)(kb + i) * N + nb + tx]);
    __syncthreads();
    for (int i = ty; i < 32; i += 8)
        dst[(size_t)(nb + i) * K + kb + tx] = tile[tx][i];
}

// ---------------------------------------------------------------------------
// Prep-only MFMA GEMM (weight composition, 256x256), both sets in one launch.
// ---------------------------------------------------------------------------
__global__ __launch_bounds__(256) void k_gemm_prep(
    const u16* __restrict__ A0, const u16* __restrict__ B0, u16* O0,
    const u16* __restrict__ A1, const u16* __restrict__ B1, u16* O1) {
    const u16* A = blockIdx.z ? A1 : A0;
    const u16* Wt = blockIdx.z ? B1 : B0;
    u16* out = blockIdx.z ? O1 : O0;
    const int m0 = blockIdx.y * 128;
    const int n0 = blockIdx.x * 128;
    const int tid = threadIdx.x;
    const int wv = tid >> 6, lane = tid & 63;
    const int quad = lane >> 4, l16 = lane & 15;
    const int wm = (wv >> 1) * 64, wn = (wv & 1) * 64;

    __shared__ u16 lA[128 * 40];
    __shared__ u16 lB[128 * 40];

    f32x4 acc[4][4];
#pragma unroll
    for (int i = 0; i < 4; i++)
#pragma unroll
        for (int j = 0; j < 4; j++) acc[i][j] = (f32x4){0.f, 0.f, 0.f, 0.f};

    const int r = tid >> 2;
    const int c = tid & 3;

    for (int k0 = 0; k0 < 256; k0 += 32) {
        __syncthreads();
        {
            const uint4 a0 = *(const uint4*)(A + (size_t)(m0 + r) * 256 + k0 + c * 8);
            const uint4 a1 = *(const uint4*)(A + (size_t)(m0 + r + 64) * 256 + k0 + c * 8);
            const uint4 b0 = *(const uint4*)(Wt + (size_t)(n0 + r) * 256 + k0 + c * 8);
            const uint4 b1 = *(const uint4*)(Wt + (size_t)(n0 + r + 64) * 256 + k0 + c * 8);
            *(uint4*)(lA + r * 40 + c * 8) = a0;
            *(uint4*)(lA + (r + 64) * 40 + c * 8) = a1;
            *(uint4*)(lB + r * 40 + c * 8) = b0;
            *(uint4*)(lB + (r + 64) * 40 + c * 8) = b1;
        }
        __syncthreads();
        bf16x8 af[4], bfr[4];
#pragma unroll
        for (int i = 0; i < 4; i++)
            af[i] = *(const bf16x8*)(lA + (wm + i * 16 + l16) * 40 + quad * 8);
#pragma unroll
        for (int j = 0; j < 4; j++)
            bfr[j] = *(const bf16x8*)(lB + (wn + j * 16 + l16) * 40 + quad * 8);
#pragma unroll
        for (int i = 0; i < 4; i++)
#pragma unroll
            for (int j = 0; j < 4; j++)
                acc[i][j] = __builtin_amdgcn_mfma_f32_16x16x32_bf16(
                    af[i], bfr[j], acc[i][j], 0, 0, 0);
    }

#pragma unroll
    for (int i = 0; i < 4; i++) {
        const int rowb = m0 + wm + i * 16 + quad * 4;
#pragma unroll
        for (int j = 0; j < 4; j++) {
            const int col = n0 + wn + j * 16 + l16;
#pragma unroll
            for (int rr = 0; rr < 4; rr++)
                out[(size_t)(rowb + rr) * 256 + col] = f2bf(acc[i][j][rr]);
        }
    }
}

// ---------------------------------------------------------------------------
// k_p12: fused P1+P2, 512 threads / 8 waves (r6-proven, unchanged).
//   r1 = x + temporal(LN1(x))@Wc1 + bc1 -> outf (fp32)
//   h2 = LN2(r1)*g+b -> hout (bf16)
// ---------------------------------------------------------------------------
__global__ __launch_bounds__(512, 4) void k_p12(
    const float* __restrict__ x, const float* __restrict__ n1g,
    const float* __restrict__ n1b, const u16* __restrict__ Wt,
    const float* __restrict__ bias, float* outf,
    const float* __restrict__ lng, const float* __restrict__ lnb,
    u16* __restrict__ hout) {
    const int b = blockIdx.y;
    const int t0 = blockIdx.x * 64;
    const size_t base = (size_t)b * TT;
    const int t = threadIdx.x;
    const int lane = t & 63, wv = t >> 6;
    const int quad = lane >> 4, l16 = lane & 15;
    const int wn = wv * 32;

    __shared__ __attribute__((aligned(16))) u16 hl[79 * 256];   // 40448 B
    __shared__ __attribute__((aligned(16))) u16 sAg[64 * 264];  // 33792 B
    float* sE = (float*)hl;  // epilogue reuse (16 x 268 f32 = 17152 B)
    __shared__ float sMean[16], sRstd[16];
    __shared__ float sG[256], sBl[256];

    if (t < 256) {
        sG[t] = lng[t];
        sBl[t] = lnb[t];
    }

    // ---- Phase A: LN1 rows into hl (proven body; 8 waves stripe rows) ----
    const int d4 = lane * 4;
    {
        const float4 gv = *(const float4*)(n1g + d4);
        const float4 bv = *(const float4*)(n1b + d4);
        for (int i = wv; i < 79; i += 8) {
            const int tt = t0 + i - 15;
            if (tt < 0) {
                *(uint2*)(hl + i * 256 + d4) = make_uint2(0u, 0u);
                continue;
            }
            const float4 v = *(const float4*)(x + (base + tt) * DD + d4);
            float s = v.x + v.y + v.z + v.w;
            float ss = v.x * v.x + v.y * v.y + v.z * v.z + v.w * v.w;
            for (int m = 1; m < 64; m <<= 1) {
                s += __shfl_xor(s, m);
                ss += __shfl_xor(ss, m);
            }
            const float mean = s * (1.0f / 256.0f);
            const float var = ss * (1.0f / 256.0f) - mean * mean;
            const float rs = rsqrtf(fmaxf(var, 0.f) + 1e-5f);
            float h[4] = {(v.x - mean) * rs * gv.x + bv.x,
                          (v.y - mean) * rs * gv.y + bv.y,
                          (v.z - mean) * rs * gv.z + bv.z,
                          (v.w - mean) * rs * gv.w + bv.w};
            *(uint2*)(hl + i * 256 + d4) = pack4(h);
        }
    }
    __syncthreads();

    // ---- Phase B: sliding-window temporal agg -> sAg (8 rows per wave) ----
    {
        float p = 1.f, s = 0.f, w15 = 1.f;
        for (int j = 0; j < 16; j++) {
            s += p;
            if (j == 15) w15 = p;
            p *= 0.9f;
        }
        const float c = 1.f / s;
        const float inv09 = 1.0f / 0.9f;
        const int tg = wv * 8;
        float g[4] = {0.f, 0.f, 0.f, 0.f};
        float pw = 1.f;
        for (int j = 0; j < 16; j++) {
            float h[4];
            unpack4(*(const uint2*)(hl + (tg + j) * 256 + d4), h);
            g[0] += pw * h[0];
            g[1] += pw * h[1];
            g[2] += pw * h[2];
            g[3] += pw * h[3];
            pw *= 0.9f;
        }
        {
            float a[4] = {c * g[0], c * g[1], c * g[2], c * g[3]};
            *(uint2*)(sAg + tg * 264 + d4) = pack4(a);
        }
        for (int ot = tg + 1; ot < tg + 8; ++ot) {
            float hold[4], hnew[4];
            unpack4(*(const uint2*)(hl + (ot - 1) * 256 + d4), hold);
            unpack4(*(const uint2*)(hl + (ot + 15) * 256 + d4), hnew);
#pragma unroll
            for (int e = 0; e < 4; e++)
                g[e] = (g[e] - hold[e]) * inv09 + w15 * hnew[e];
            float a[4] = {c * g[0], c * g[1], c * g[2], c * g[3]};
            *(uint2*)(sAg + ot * 264 + d4) = pack4(a);
        }
    }
    __syncthreads();

    // ---- Phase C: GEMM, barrier-free K-loop; 32 N-cols per wave ----
    f32x4 acc[4][2];
#pragma unroll
    for (int i = 0; i < 4; i++)
#pragma unroll
        for (int j = 0; j < 2; j++) acc[i][j] = (f32x4){0.f, 0.f, 0.f, 0.f};
#pragma unroll
    for (int ks = 0; ks < 8; ks++) {
        bf16x8 bfr[2], af[4];
#pragma unroll
        for (int j = 0; j < 2; j++)
            bfr[j] = *(const bf16x8*)(Wt + (size_t)(wn + j * 16 + l16) * 256 +
                                      ks * 32 + quad * 8);
#pragma unroll
        for (int i = 0; i < 4; i++)
            af[i] = *(const bf16x8*)(sAg + (i * 16 + l16) * 264 + ks * 32 +
                                     quad * 8);
#pragma unroll
        for (int i = 0; i < 4; i++)
#pragma unroll
            for (int j = 0; j < 2; j++)
                acc[i][j] = __builtin_amdgcn_mfma_f32_16x16x32_bf16(
                    af[i], bfr[j], acc[i][j], 0, 0, 0);
    }

    // ---- Phase D: epilogue (res=x, fp32 out, LN2 bf16 out) ----
    float bvl[2];
#pragma unroll
    for (int j = 0; j < 2; j++) bvl[j] = bias[wn + j * 16 + l16];

    const int row = t >> 5;         // 0..15
    const int colb = (t & 31) * 8;  // 0..248
    for (int cch = 0; cch < 4; cch++) {
        const size_t grow = base + t0 + cch * 16 + row;
        __syncthreads();  // guard sE overlay of hl + prior chunk reads
        {
            const float* rp = x + grow * 256 + colb;
            float* sp = sE + row * 268 + colb;
#pragma unroll
            for (int q = 0; q < 2; q++)
                *(float4*)(sp + q * 4) = *(const float4*)(rp + q * 4);
        }
        __syncthreads();
#pragma unroll
        for (int j = 0; j < 2; j++) {
#pragma unroll
            for (int rr = 0; rr < 4; rr++) {
                const int rl = quad * 4 + rr;
                const int ad = rl * 268 + wn + j * 16 + l16;
                sE[ad] += acc[cch][j][rr] + bvl[j];
            }
        }
        __syncthreads();
#pragma unroll
        for (int r4 = 0; r4 < 2; r4++) {
            const int rl = wv * 2 + r4;
            const float4 vv = *(const float4*)(sE + rl * 268 + lane * 4);
            float s = vv.x + vv.y + vv.z + vv.w;
            float ss = vv.x * vv.x + vv.y * vv.y + vv.z * vv.z + vv.w * vv.w;
            for (int m = 1; m < 64; m <<= 1) {
                s += __shfl_xor(s, m);
                ss += __shfl_xor(ss, m);
            }
            if (lane == 0) {
                const float mean = s * (1.0f / 256.0f);
                const float var = ss * (1.0f / 256.0f) - mean * mean;
                sMean[rl] = mean;
                sRstd[rl] = rsqrtf(fmaxf(var, 0.f) + 1e-5f);
            }
        }
        __syncthreads();
        const float* sp = sE + row * 268 + colb;
        {
            float* op = outf + grow * 256 + colb;
#pragma unroll
            for (int q = 0; q < 2; q++)
                *(float4*)(op + q * 4) = *(const float4*)(sp + q * 4);
        }
        {
            const float m = sMean[row], rs = sRstd[row];
            float h[8];
#pragma unroll
            for (int e = 0; e < 8; e++)
                h[e] = (sp[e] - m) * rs * sG[colb + e] + sBl[colb + e];
            u16* hp = hout + grow * 256 + colb;
            *(uint4*)hp = pack8(h);
        }
    }
}

// ---------------------------------------------------------------------------
// k_mega2: P3 (3-tap neighbor GEMM + residual + LN3 out), 512 threads
// (r6-proven exact body, lb(512,4)).
// ---------------------------------------------------------------------------
__global__ __launch_bounds__(512, 4) void k_mega2(
    const u16* __restrict__ A,      // [NTOK][256] bf16 (h2)
    const u16* __restrict__ Wt,     // [256][256] bf16 (N-major)
    const float* __restrict__ bias, // [256] composed
    const float* res,               // [NTOK][256] fp32 (may alias outf)
    float* outf,                    // [NTOK][256] fp32
    const float* __restrict__ lng, const float* __restrict__ lnb,
    u16* __restrict__ hout) {       // [NTOK][256] bf16 LN output
    const int m0 = blockIdx.x * 64;
    const int t = threadIdx.x;
    const int lane = t & 63, wv = t >> 6;
    const int quad = lane >> 4, l16 = lane & 15;
    const int wn = wv * 32;

    __shared__ __attribute__((aligned(16))) u16 sA[8 * 64 * 40];
    float* sE = (float*)sA;  // epilogue reuse: 16 x 268 f32
    __shared__ float sMean[16], sRstd[16];
    __shared__ float sG[256], sBl[256];

    if (t < 256) {
        sG[t] = lng[t];
        sBl[t] = lnb[t];
    }

    // ---- stage A = 3-tap neighbor mean (edge-replicate per batch) ----
#pragma unroll
    for (int q = 0; q < 4; q++) {
        const int id = q * 512 + t;
        const int arow = id >> 5;      // 0..63
        const int c8 = (id & 31) * 8;  // 0..248
        const int ks = c8 >> 5;
        const int kc = c8 & 31;
        const int gr = m0 + arow;
        const int rm = ((gr & (TT - 1)) == 0) ? gr : gr - 1;
        const int rp = (((gr + 1) & (TT - 1)) == 0) ? gr : gr + 1;
        float v0[8], v1[8], v2[8], o[8];
        unpack8(*(const uint4*)(A + (size_t)rm * 256 + c8), v0);
        unpack8(*(const uint4*)(A + (size_t)gr * 256 + c8), v1);
        unpack8(*(const uint4*)(A + (size_t)rp * 256 + c8), v2);
#pragma unroll
        for (int e = 0; e < 8; e++)
            o[e] = (v0[e] + v1[e] + v2[e]) * (1.0f / 3.0f);
        *(uint4*)(sA + (ks * 64 + arow) * 40 + kc) = pack8(o);
    }

    f32x4 acc[4][2];
#pragma unroll
    for (int i = 0; i < 4; i++)
#pragma unroll
        for (int j = 0; j < 2; j++) acc[i][j] = (f32x4){0.f, 0.f, 0.f, 0.f};

    __syncthreads();

    // ---- K-loop: no barriers; B straight from L2; 32 N-cols per wave ----
#pragma unroll
    for (int ks = 0; ks < 8; ks++) {
        bf16x8 bfr[2], af[4];
#pragma unroll
        for (int j = 0; j < 2; j++)
            bfr[j] = *(const bf16x8*)(Wt + (size_t)(wn + j * 16 + l16) * 256 +
                                      ks * 32 + quad * 8);
#pragma unroll
        for (int i = 0; i < 4; i++)
            af[i] = *(const bf16x8*)(sA + (ks * 64 + i * 16 + l16) * 40 +
                                     quad * 8);
#pragma unroll
        for (int i = 0; i < 4; i++)
#pragma unroll
            for (int j = 0; j < 2; j++)
                acc[i][j] = __builtin_amdgcn_mfma_f32_16x16x32_bf16(
                    af[i], bfr[j], acc[i][j], 0, 0, 0);
    }

    // ---- epilogue: res + bias add, fp32 store, LN bf16 store ----
    float bvl[2];
#pragma unroll
    for (int j = 0; j < 2; j++) bvl[j] = bias[wn + j * 16 + l16];

    const int row = t >> 5;         // 0..15
    const int colb = (t & 31) * 8;  // 0..248
    for (int cch = 0; cch < 4; cch++) {
        const int gr = m0 + cch * 16 + row;
        __syncthreads();  // guard sE/sA reuse + prior chunk reads
        {
            const float* rp = res + (size_t)gr * 256 + colb;
            float* sp = sE + row * 268 + colb;
#pragma unroll
            for (int q = 0; q < 2; q++)
                *(float4*)(sp + q * 4) = *(const float4*)(rp + q * 4);
        }
        __syncthreads();
#pragma unroll
        for (int j = 0; j < 2; j++) {
#pragma unroll
            for (int rr = 0; rr < 4; rr++) {
                const int rl = quad * 4 + rr;
                const int ad = rl * 268 + wn + j * 16 + l16;
                sE[ad] += acc[cch][j][rr] + bvl[j];
            }
        }
        __syncthreads();
#pragma unroll
        for (int r4 = 0; r4 < 2; r4++) {
            const int rl = wv * 2 + r4;
            const float4 vv = *(const float4*)(sE + rl * 268 + lane * 4);
            float s = vv.x + vv.y + vv.z + vv.w;
            float ss = vv.x * vv.x + vv.y * vv.y + vv.z * vv.z + vv.w * vv.w;
            for (int m = 1; m < 64; m <<= 1) {
                s += __shfl_xor(s, m);
                ss += __shfl_xor(ss, m);
            }
            if (lane == 0) {
                const float mean = s * (1.0f / 256.0f);
                const float var = ss * (1.0f / 256.0f) - mean * mean;
                sMean[rl] = mean;
                sRstd[rl] = rsqrtf(fmaxf(var, 0.f) + 1e-5f);
            }
        }
        __syncthreads();
        const float* sp = sE + row * 268 + colb;
        {
            float* op = outf + (size_t)gr * 256 + colb;
#pragma unroll
            for (int q = 0; q < 2; q++)
                *(float4*)(op + q * 4) = *(const float4*)(sp + q * 4);
        }
        {
            const float m = sMean[row], rs = sRstd[row];
            float h[8];
#pragma unroll
            for (int e = 0; e < 8; e++)
                h[e] = (sp[e] - m) * rs * sG[colb + e] + sBl[colb + e];
            u16* hp = hout + (size_t)gr * 256 + colb;
            *(uint4*)hp = pack8(h);
        }
    }
}

// ---------------------------------------------------------------------------
// k_ffn: out = res + gelu(A@W1+b1)@W2 + b2, 512 threads / 8 waves.
// r11 = r10 resubmitted (infra flake; kernel audited race-free):
// barrier-convoy cut, 21 -> 5 barriers, nothing else changed.
//  (a) Epilogue in registers: each lane reads res / writes out directly at
//      its C-fragment coords (rows m0+cch*16+quad*4+rr, cols wn+jj*16+l16 —
//      bijective over the 64x256 tile; res/out alias per-element within one
//      thread -> safe). Removes 12 barriers + the epilogue LDS round trip.
//  (b) sT double-buffered: write sT[j&1]; ONE barrier; GEMM2 reads it. The
//      next overwrite of sT[j&1] (iter j+2's GELU) is after barrier(j+1),
//      and barrier(j+1) is after GEMM2(j) in every wave's program order ->
//      all readers done before re-write. Removes 4 barriers.
// LDS: sA 36864 + sT 2x16896 = 70656 B -> 2 blocks/CU. lb(512,4),
// VGPR ~64-110 (no spill risk).
// ---------------------------------------------------------------------------
__global__ __launch_bounds__(512, 4) void k_ffn(
    const u16* __restrict__ A,    // [NTOK][256] bf16 (h3)
    const u16* __restrict__ W1T,  // [512][256] bf16
    const float* __restrict__ b1, // [512]
    const u16* __restrict__ W2T,  // [256][512] bf16
    const float* __restrict__ b2, // [256]
    const float* res,             // [NTOK][256] fp32 (r2) — may alias out
    float* out) {
    const int m0 = blockIdx.x * 64;
    const int t = threadIdx.x;
    const int lane = t & 63, wv = t >> 6;
    const int quad = lane >> 4, l16 = lane & 15;
    const int wn = wv * 32;

    __shared__ __attribute__((aligned(16))) u16 sA[8 * 64 * 36];  // 36864 B
    __shared__ __attribute__((aligned(16))) u16 sT[2][64 * 132];  // 33792 B

    // ---- stage A tile (64 x 256 bf16 = 2048 uint4, coalesced) ----
#pragma unroll
    for (int q = 0; q < 4; q++) {
        const int id = q * 512 + t;
        const int arow = id >> 5;        // 0..63
        const int c8 = (id & 31) * 8;    // 0..248
        const int ks = c8 >> 5;          // 0..7
        const int kc = c8 & 31;          // 0,8,16,24
        *(uint4*)(sA + (ks * 64 + arow) * 36 + kc) =
            *(const uint4*)(A + (size_t)(m0 + arow) * 256 + c8);
    }

    f32x4 acc2[4][2];
#pragma unroll
    for (int i = 0; i < 4; i++)
#pragma unroll
        for (int jj = 0; jj < 2; jj++) acc2[i][jj] = (f32x4){0.f, 0.f, 0.f, 0.f};

    __syncthreads();

    for (int j4 = 0; j4 < 4; j4++) {
        u16* sTc = sT[j4 & 1];
        // ---- GEMM1: wave wv computes T1[:, j4*128 + wv*16 .. +15] ----
        const int n1 = j4 * 128 + wv * 16 + l16;
        bf16x8 bw[8];
#pragma unroll
        for (int ks = 0; ks < 8; ks++)
            bw[ks] = *(const bf16x8*)(W1T + (size_t)n1 * 256 + ks * 32 + quad * 8);
        f32x4 acc1[4];
#pragma unroll
        for (int i = 0; i < 4; i++) acc1[i] = (f32x4){0.f, 0.f, 0.f, 0.f};
#pragma unroll
        for (int ks = 0; ks < 8; ks++) {
#pragma unroll
            for (int i = 0; i < 4; i++) {
                const bf16x8 af = *(const bf16x8*)(
                    sA + (ks * 64 + i * 16 + l16) * 36 + quad * 8);
                acc1[i] = __builtin_amdgcn_mfma_f32_16x16x32_bf16(
                    af, bw[ks], acc1[i], 0, 0, 0);
            }
        }
        // ---- prefetch W2 fragments for this chunk (independent of sT) ----
        bf16x8 bw2[8];
#pragma unroll
        for (int kh = 0; kh < 4; kh++)
#pragma unroll
            for (int jj = 0; jj < 2; jj++)
                bw2[kh * 2 + jj] = *(const bf16x8*)(
                    W2T + (size_t)(wn + jj * 16 + l16) * 512 + j4 * 128 +
                    kh * 32 + quad * 8);
        // ---- bias + exact GELU, pack to sTc (row quad*4+rr, col wv*16+l16) -
        const float b1l = b1[n1];
#pragma unroll
        for (int i = 0; i < 4; i++)
#pragma unroll
            for (int rr = 0; rr < 4; rr++) {
                float v = acc1[i][rr] + b1l;
                v = 0.5f * v * (1.0f + erff(v * 0.70710678118654752f));
                sTc[(i * 16 + quad * 4 + rr) * 132 + wv * 16 + l16] = f2bf(v);
            }
        __syncthreads();  // the ONLY barrier per chunk (dbuf covers reuse)
        // ---- GEMM2: acc2 += T1chunk @ W2[j4*128 .. +127][:] ----
#pragma unroll
        for (int kh = 0; kh < 4; kh++) {
#pragma unroll
            for (int i = 0; i < 4; i++) {
                const bf16x8 af = *(const bf16x8*)(
                    sTc + (i * 16 + l16) * 132 + kh * 32 + quad * 8);
#pragma unroll
                for (int jj = 0; jj < 2; jj++)
                    acc2[i][jj] = __builtin_amdgcn_mfma_f32_16x16x32_bf16(
                        af, bw2[kh * 2 + jj], acc2[i][jj], 0, 0, 0);
            }
        }
    }

    // ---- epilogue: out = acc2 + b2 + res, register-direct, no barriers ----
    // Lane owns rows m0 + cch*16 + quad*4 + rr, cols wn + jj*16 + l16.
    // Per (jj,rr) wave-inst: 16 lanes x 4B = 64B contiguous segments.
    float bvl[2];
#pragma unroll
    for (int jj = 0; jj < 2; jj++) bvl[jj] = b2[wn + jj * 16 + l16];
#pragma unroll
    for (int cch = 0; cch < 4; cch++) {
#pragma unroll
        for (int rr = 0; rr < 4; rr++) {
            const size_t grow = (size_t)(m0 + cch * 16 + quad * 4 + rr) * 256;
#pragma unroll
            for (int jj = 0; jj < 2; jj++) {
                const size_t ad = grow + wn + jj * 16 + l16;
                out[ad] = res[ad] + acc2[cch][jj][rr] + bvl[jj];
            }
        }
    }
}

// ---------------------------------------------------------------------------
extern "C" void kernel_launch(void* const* d_in, const int* in_sizes, int n_in,
                              void* d_out, int out_size, void* d_ws,
                              size_t ws_size, hipStream_t stream) {
    const float* x = (const float*)d_in[0];
    const float* n1g = (const float*)d_in[1];
    const float* n1b = (const float*)d_in[2];
    const float* n2g = (const float*)d_in[3];
    const float* n2b = (const float*)d_in[4];
    const float* n3g = (const float*)d_in[5];
    const float* n3b = (const float*)d_in[6];
    const float* tWv = (const float*)d_in[7];
    const float* tbv = (const float*)d_in[8];
    const float* tWo = (const float*)d_in[9];
    const float* tbo = (const float*)d_in[10];
    const float* aWv = (const float*)d_in[11];
    const float* abv = (const float*)d_in[12];
    const float* aWo = (const float*)d_in[13];
    const float* abo = (const float*)d_in[14];
    const float* fW1 = (const float*)d_in[15];
    const float* fb1 = (const float*)d_in[16];
    const float* fW2 = (const float*)d_in[17];
    const float* fb2 = (const float*)d_in[18];
    float* outp = (float*)d_out;

    u16* wq = (u16*)d_ws;
    u16* tWoT = wq;                      //  65536  [256][256]
    u16* aWoT = wq + 65536;              //  65536
    u16* fW1T = wq + 131072;             // 131072  [512][256]
    u16* fW2T = wq + 262144;             // 131072  [256][512]
    u16* WcT1 = wq + 393216;             //  65536
    u16* WcT2 = wq + 458752;             //  65536
    u16* tWvB = wq + 524288;             //  65536
    u16* aWvB = wq + 589824;             //  65536
    float* bc1 = (float*)(wq + 655360);  //  256 fp32
    float* bc2 = (float*)(wq + 655872);  //  256 fp32
    const size_t W_ELEMS = 656384;
    const size_t SLOT = (size_t)NTOK * 256;
    u16* slot1 = wq + W_ELEMS;
    u16* slot2 = slot1 + SLOT;

    const size_t need = (W_ELEMS + 3 * SLOT) * 2;  // ~97.3 MB (fits: r5)
    if (ws_size < need) {
        k_diag<<<dim3(NTOK), 256, 0, stream>>>(outp,
                                               512.0f + (float)(ws_size >> 20));
        return;
    }

    // --- weight prep (2 launches) ---
    k_transpose<<<dim3(16, 16, 8), 256, 0, stream>>>(
        tWo, aWo, fW1, fW2, tWv, aWv, tWoT, aWoT, fW1T, fW2T, tWvB, aWvB,
        tbv, tbo, abv, abo, bc1, bc2);
    k_gemm_prep<<<dim3(2, 2, 2), 256, 0, stream>>>(tWoT, tWvB, WcT1, aWoT,
                                                   aWvB, WcT2);

    // P1+P2 fused: r1 = x + temporal(LN1(x))@Wc1 + bc1 -> d_out (fp32);
    //              h2 = LN2(r1) -> slot2 (bf16)
    k_p12<<<dim3(TT / 64, BB), 512, 0, stream>>>(x, n1g, n1b, WcT1, bc1, outp,
                                                 n2g, n2b, slot2);

    // P3: r2 = r1 + nbr(h2)@Wc2 + bc2 -> d_out (in-place); h3 = LN3 -> slot1
    k_mega2<<<dim3(NTOK / 64), 512, 0, stream>>>(slot2, WcT2, bc2, outp, outp,
                                                 n3g, n3b, slot1);

    // P4+P5+P6 fused: out = r2 + gelu(h3@W1+b1)@W2 + b2 (in-place residual)
    k_ffn<<<dim3(NTOK / 64), 512, 0, stream>>>(slot1, fW1T, fb1, fW2T, fb2,
                                               outp, outp);
}

// Round 12
// 371.246 us; speedup vs baseline: 1.0259x; 1.0259x over previous
//
#include <hip/hip_runtime.h>
#include <cstdint>
#include <cstddef>

// Problem constants (B=8, T=8192, D=256, H=16, K=3, decay=0.9, eps=1e-5)
// I/O dtype: fp32. Internal staging: bf16 (MFMA). ws >= 97.3 MB (confirmed r5).
#define TT 8192
#define BB 8
#define DD 256
#define NTOK (BB * TT)

typedef unsigned short u16;
typedef unsigned int u32;

typedef __attribute__((ext_vector_type(8))) short bf16x8;
typedef __attribute__((ext_vector_type(4))) float f32x4;

__device__ __forceinline__ float bf2f(u16 u) {
    u32 v = ((u32)u) << 16;
    float f;
    __builtin_memcpy(&f, &v, 4);
    return f;
}

__device__ __forceinline__ u16 f2bf(float f) {
    u32 v;
    __builtin_memcpy(&v, &f, 4);
    u32 r = (v + 0x7FFFu + ((v >> 16) & 1u)) >> 16;  // RNE
    return (u16)r;
}

__device__ __forceinline__ uint2 pack4(const float* v) {
    uint2 p;
    p.x = (u32)f2bf(v[0]) | ((u32)f2bf(v[1]) << 16);
    p.y = (u32)f2bf(v[2]) | ((u32)f2bf(v[3]) << 16);
    return p;
}

__device__ __forceinline__ void unpack4(uint2 p, float* v) {
    v[0] = bf2f((u16)(p.x & 0xFFFFu));
    v[1] = bf2f((u16)(p.x >> 16));
    v[2] = bf2f((u16)(p.y & 0xFFFFu));
    v[3] = bf2f((u16)(p.y >> 16));
}

__device__ __forceinline__ uint4 pack8(const float* v) {
    uint4 p;
    p.x = (u32)f2bf(v[0]) | ((u32)f2bf(v[1]) << 16);
    p.y = (u32)f2bf(v[2]) | ((u32)f2bf(v[3]) << 16);
    p.z = (u32)f2bf(v[4]) | ((u32)f2bf(v[5]) << 16);
    p.w = (u32)f2bf(v[6]) | ((u32)f2bf(v[7]) << 16);
    return p;
}

__device__ __forceinline__ void unpack8(uint4 p, float* v) {
    v[0] = bf2f((u16)(p.x & 0xFFFFu));
    v[1] = bf2f((u16)(p.x >> 16));
    v[2] = bf2f((u16)(p.y & 0xFFFFu));
    v[3] = bf2f((u16)(p.y >> 16));
    v[4] = bf2f((u16)(p.z & 0xFFFFu));
    v[5] = bf2f((u16)(p.z >> 16));
    v[6] = bf2f((u16)(p.w & 0xFFFFu));
    v[7] = bf2f((u16)(p.w >> 16));
}

// ---------------------------------------------------------------------------
__global__ __launch_bounds__(256) void k_diag(float* out, float code) {
    out[(size_t)blockIdx.x * 256 + threadIdx.x] = code;
}

// ---------------------------------------------------------------------------
// Weight transpose/convert fp32 -> bf16 (proven) + bias compose folded in
// (z=6,7).
// ---------------------------------------------------------------------------
__global__ __launch_bounds__(256) void k_transpose(
    const float* s0, const float* s1, const float* s2, const float* s3,
    const float* s4, const float* s5,
    u16* d0, u16* d1, u16* d2, u16* d3, u16* d4, u16* d5,
    const float* tbv, const float* tbo, const float* abv, const float* abo,
    float* bc1, float* bc2) {
    const int z = blockIdx.z;
    if (z >= 6) {  // bias compose: bc[n] = sum_j bv[j]*Wo[j][n] + bo[n]
        if (blockIdx.x || blockIdx.y) return;
        const float* bv = (z == 7) ? abv : tbv;
        const float* Wo = (z == 7) ? s1 : s0;  // aWo : tWo (fp32 sources)
        const float* bo = (z == 7) ? abo : tbo;
        float* bc = (z == 7) ? bc2 : bc1;
        const int n = threadIdx.x;
        float s = bo[n];
        for (int j = 0; j < 256; j++) s += bv[j] * Wo[j * 256 + n];
        bc[n] = s;
        return;
    }
    const float* src;
    u16* dst;
    int K, N, tr;
    switch (z) {
        case 0: src = s0; dst = d0; K = 256; N = 256; tr = 1; break;
        case 1: src = s1; dst = d1; K = 256; N = 256; tr = 1; break;
        case 2: src = s2; dst = d2; K = 256; N = 512; tr = 1; break;
        case 3: src = s3; dst = d3; K = 512; N = 256; tr = 1; break;
        case 4: src = s4; dst = d4; K = 256; N = 256; tr = 0; break;
        default: src = s5; dst = d5; K = 256; N = 256; tr = 0; break;
    }
    const int nb = blockIdx.x * 32, kb = blockIdx.y * 32;
    if (nb >= N || kb >= K) return;
    const int tx = threadIdx.x & 31, ty = threadIdx.x >> 5;
    if (!tr) {
        for (int i = ty; i < 32; i += 8)
            dst[(size_t)(kb + i) * N + nb + tx] =
                f2bf(src[(size_t)(kb + i) * N + nb + tx]);
        return;
    }
    __shared__ u16 tile[32][33];
    for (int i = ty; i < 32; i += 8)
        tile[i][tx] = f2bf(src[(size_t)(kb + i) * N + nb + tx]);
    __syncthreads();
    for (int i = ty; i < 32; i += 8)
        dst[(size_t)(nb + i) * K + kb + tx] = tile[tx][i];
}

// ---------------------------------------------------------------------------
// Prep-only MFMA GEMM (weight composition, 256x256), both sets in one launch.
// ---------------------------------------------------------------------------
__global__ __launch_bounds__(256) void k_gemm_prep(
    const u16* __restrict__ A0, const u16* __restrict__ B0, u16* O0,
    const u16* __restrict__ A1, const u16* __restrict__ B1, u16* O1) {
    const u16* A = blockIdx.z ? A1 : A0;
    const u16* Wt = blockIdx.z ? B1 : B0;
    u16* out = blockIdx.z ? O1 : O0;
    const int m0 = blockIdx.y * 128;
    const int n0 = blockIdx.x * 128;
    const int tid = threadIdx.x;
    const int wv = tid >> 6, lane = tid & 63;
    const int quad = lane >> 4, l16 = lane & 15;
    const int wm = (wv >> 1) * 64, wn = (wv & 1) * 64;

    __shared__ u16 lA[128 * 40];
    __shared__ u16 lB[128 * 40];

    f32x4 acc[4][4];
#pragma unroll
    for (int i = 0; i < 4; i++)
#pragma unroll
        for (int j = 0; j < 4; j++) acc[i][j] = (f32x4){0.f, 0.f, 0.f, 0.f};

    const int r = tid >> 2;
    const int c = tid & 3;

    for (int k0 = 0; k0 < 256; k0 += 32) {
        __syncthreads();
        {
            const uint4 a0 = *(const uint4*)(A + (size_t)(m0 + r) * 256 + k0 + c * 8);
            const uint4 a1 = *(const uint4*)(A + (size_t)(m0 + r + 64) * 256 + k0 + c * 8);
            const uint4 b0 = *(const uint4*)(Wt + (size_t)(n0 + r) * 256 + k0 + c * 8);
            const uint4 b1 = *(const uint4*)(Wt + (size_t)(n0 + r + 64) * 256 + k0 + c * 8);
            *(uint4*)(lA + r * 40 + c * 8) = a0;
            *(uint4*)(lA + (r + 64) * 40 + c * 8) = a1;
            *(uint4*)(lB + r * 40 + c * 8) = b0;
            *(uint4*)(lB + (r + 64) * 40 + c * 8) = b1;
        }
        __syncthreads();
        bf16x8 af[4], bfr[4];
#pragma unroll
        for (int i = 0; i < 4; i++)
            af[i] = *(const bf16x8*)(lA + (wm + i * 16 + l16) * 40 + quad * 8);
#pragma unroll
        for (int j = 0; j < 4; j++)
            bfr[j] = *(const bf16x8*)(lB + (wn + j * 16 + l16) * 40 + quad * 8);
#pragma unroll
        for (int i = 0; i < 4; i++)
#pragma unroll
            for (int j = 0; j < 4; j++)
                acc[i][j] = __builtin_amdgcn_mfma_f32_16x16x32_bf16(
                    af[i], bfr[j], acc[i][j], 0, 0, 0);
    }

#pragma unroll
    for (int i = 0; i < 4; i++) {
        const int rowb = m0 + wm + i * 16 + quad * 4;
#pragma unroll
        for (int j = 0; j < 4; j++) {
            const int col = n0 + wn + j * 16 + l16;
#pragma unroll
            for (int rr = 0; rr < 4; rr++)
                out[(size_t)(rowb + rr) * 256 + col] = f2bf(acc[i][j][rr]);
        }
    }
}

// ---------------------------------------------------------------------------
// k_p12: fused P1+P2, 512 threads / 8 waves (r6-proven, unchanged).
//   r1 = x + temporal(LN1(x))@Wc1 + bc1 -> outf (fp32)
//   h2 = LN2(r1)*g+b -> hout (bf16)
// ---------------------------------------------------------------------------
__global__ __launch_bounds__(512, 4) void k_p12(
    const float* __restrict__ x, const float* __restrict__ n1g,
    const float* __restrict__ n1b, const u16* __restrict__ Wt,
    const float* __restrict__ bias, float* outf,
    const float* __restrict__ lng, const float* __restrict__ lnb,
    u16* __restrict__ hout) {
    const int b = blockIdx.y;
    const int t0 = blockIdx.x * 64;
    const size_t base = (size_t)b * TT;
    const int t = threadIdx.x;
    const int lane = t & 63, wv = t >> 6;
    const int quad = lane >> 4, l16 = lane & 15;
    const int wn = wv * 32;

    __shared__ __attribute__((aligned(16))) u16 hl[79 * 256];   // 40448 B
    __shared__ __attribute__((aligned(16))) u16 sAg[64 * 264];  // 33792 B
    float* sE = (float*)hl;  // epilogue reuse (16 x 268 f32 = 17152 B)
    __shared__ float sMean[16], sRstd[16];
    __shared__ float sG[256], sBl[256];

    if (t < 256) {
        sG[t] = lng[t];
        sBl[t] = lnb[t];
    }

    // ---- Phase A: LN1 rows into hl (proven body; 8 waves stripe rows) ----
    const int d4 = lane * 4;
    {
        const float4 gv = *(const float4*)(n1g + d4);
        const float4 bv = *(const float4*)(n1b + d4);
        for (int i = wv; i < 79; i += 8) {
            const int tt = t0 + i - 15;
            if (tt < 0) {
                *(uint2*)(hl + i * 256 + d4) = make_uint2(0u, 0u);
                continue;
            }
            const float4 v = *(const float4*)(x + (base + tt) * DD + d4);
            float s = v.x + v.y + v.z + v.w;
            float ss = v.x * v.x + v.y * v.y + v.z * v.z + v.w * v.w;
            for (int m = 1; m < 64; m <<= 1) {
                s += __shfl_xor(s, m);
                ss += __shfl_xor(ss, m);
            }
            const float mean = s * (1.0f / 256.0f);
            const float var = ss * (1.0f / 256.0f) - mean * mean;
            const float rs = rsqrtf(fmaxf(var, 0.f) + 1e-5f);
            float h[4] = {(v.x - mean) * rs * gv.x + bv.x,
                          (v.y - mean) * rs * gv.y + bv.y,
                          (v.z - mean) * rs * gv.z + bv.z,
                          (v.w - mean) * rs * gv.w + bv.w};
            *(uint2*)(hl + i * 256 + d4) = pack4(h);
        }
    }
    __syncthreads();

    // ---- Phase B: sliding-window temporal agg -> sAg (8 rows per wave) ----
    {
        float p = 1.f, s = 0.f, w15 = 1.f;
        for (int j = 0; j < 16; j++) {
            s += p;
            if (j == 15) w15 = p;
            p *= 0.9f;
        }
        const float c = 1.f / s;
        const float inv09 = 1.0f / 0.9f;
        const int tg = wv * 8;
        float g[4] = {0.f, 0.f, 0.f, 0.f};
        float pw = 1.f;
        for (int j = 0; j < 16; j++) {
            float h[4];
            unpack4(*(const uint2*)(hl + (tg + j) * 256 + d4), h);
            g[0] += pw * h[0];
            g[1] += pw * h[1];
            g[2] += pw * h[2];
            g[3] += pw * h[3];
            pw *= 0.9f;
        }
        {
            float a[4] = {c * g[0], c * g[1], c * g[2], c * g[3]};
            *(uint2*)(sAg + tg * 264 + d4) = pack4(a);
        }
        for (int ot = tg + 1; ot < tg + 8; ++ot) {
            float hold[4], hnew[4];
            unpack4(*(const uint2*)(hl + (ot - 1) * 256 + d4), hold);
            unpack4(*(const uint2*)(hl + (ot + 15) * 256 + d4), hnew);
#pragma unroll
            for (int e = 0; e < 4; e++)
                g[e] = (g[e] - hold[e]) * inv09 + w15 * hnew[e];
            float a[4] = {c * g[0], c * g[1], c * g[2], c * g[3]};
            *(uint2*)(sAg + ot * 264 + d4) = pack4(a);
        }
    }
    __syncthreads();

    // ---- Phase C: GEMM, barrier-free K-loop; 32 N-cols per wave ----
    f32x4 acc[4][2];
#pragma unroll
    for (int i = 0; i < 4; i++)
#pragma unroll
        for (int j = 0; j < 2; j++) acc[i][j] = (f32x4){0.f, 0.f, 0.f, 0.f};
#pragma unroll
    for (int ks = 0; ks < 8; ks++) {
        bf16x8 bfr[2], af[4];
#pragma unroll
        for (int j = 0; j < 2; j++)
            bfr[j] = *(const bf16x8*)(Wt + (size_t)(wn + j * 16 + l16) * 256 +
                                      ks * 32 + quad * 8);
#pragma unroll
        for (int i = 0; i < 4; i++)
            af[i] = *(const bf16x8*)(sAg + (i * 16 + l16) * 264 + ks * 32 +
                                     quad * 8);
#pragma unroll
        for (int i = 0; i < 4; i++)
#pragma unroll
            for (int j = 0; j < 2; j++)
                acc[i][j] = __builtin_amdgcn_mfma_f32_16x16x32_bf16(
                    af[i], bfr[j], acc[i][j], 0, 0, 0);
    }

    // ---- Phase D: epilogue (res=x, fp32 out, LN2 bf16 out) ----
    float bvl[2];
#pragma unroll
    for (int j = 0; j < 2; j++) bvl[j] = bias[wn + j * 16 + l16];

    const int row = t >> 5;         // 0..15
    const int colb = (t & 31) * 8;  // 0..248
    for (int cch = 0; cch < 4; cch++) {
        const size_t grow = base + t0 + cch * 16 + row;
        __syncthreads();  // guard sE overlay of hl + prior chunk reads
        {
            const float* rp = x + grow * 256 + colb;
            float* sp = sE + row * 268 + colb;
#pragma unroll
            for (int q = 0; q < 2; q++)
                *(float4*)(sp + q * 4) = *(const float4*)(rp + q * 4);
        }
        __syncthreads();
#pragma unroll
        for (int j = 0; j < 2; j++) {
#pragma unroll
            for (int rr = 0; rr < 4; rr++) {
                const int rl = quad * 4 + rr;
                const int ad = rl * 268 + wn + j * 16 + l16;
                sE[ad] += acc[cch][j][rr] + bvl[j];
            }
        }
        __syncthreads();
#pragma unroll
        for (int r4 = 0; r4 < 2; r4++) {
            const int rl = wv * 2 + r4;
            const float4 vv = *(const float4*)(sE + rl * 268 + lane * 4);
            float s = vv.x + vv.y + vv.z + vv.w;
            float ss = vv.x * vv.x + vv.y * vv.y + vv.z * vv.z + vv.w * vv.w;
            for (int m = 1; m < 64; m <<= 1) {
                s += __shfl_xor(s, m);
                ss += __shfl_xor(ss, m);
            }
            if (lane == 0) {
                const float mean = s * (1.0f / 256.0f);
                const float var = ss * (1.0f / 256.0f) - mean * mean;
                sMean[rl] = mean;
                sRstd[rl] = rsqrtf(fmaxf(var, 0.f) + 1e-5f);
            }
        }
        __syncthreads();
        const float* sp = sE + row * 268 + colb;
        {
            float* op = outf + grow * 256 + colb;
#pragma unroll
            for (int q = 0; q < 2; q++)
                *(float4*)(op + q * 4) = *(const float4*)(sp + q * 4);
        }
        {
            const float m = sMean[row], rs = sRstd[row];
            float h[8];
#pragma unroll
            for (int e = 0; e < 8; e++)
                h[e] = (sp[e] - m) * rs * sG[colb + e] + sBl[colb + e];
            u16* hp = hout + grow * 256 + colb;
            *(uint4*)hp = pack8(h);
        }
    }
}

// ---------------------------------------------------------------------------
// k_mega2: P3 (3-tap neighbor GEMM + residual + LN3 out), 512 threads.
// r12: r6-proven body + T14 res-prefetch — the epilogue's res loads were the
// kernel TAIL (latency hidden by nothing); issue them at kernel entry into
// 32 VGPR (rows owned exclusively per block -> early read safe), epilogue
// writes them to sE instead of loading. +32 VGPR (~110 total, under the 128
// cap of lb(512,4) — no r8-style spill risk).
// ---------------------------------------------------------------------------
__global__ __launch_bounds__(512, 4) void k_mega2(
    const u16* __restrict__ A,      // [NTOK][256] bf16 (h2)
    const u16* __restrict__ Wt,     // [256][256] bf16 (N-major)
    const float* __restrict__ bias, // [256] composed
    const float* res,               // [NTOK][256] fp32 (may alias outf)
    float* outf,                    // [NTOK][256] fp32
    const float* __restrict__ lng, const float* __restrict__ lnb,
    u16* __restrict__ hout) {       // [NTOK][256] bf16 LN output
    const int m0 = blockIdx.x * 64;
    const int t = threadIdx.x;
    const int lane = t & 63, wv = t >> 6;
    const int quad = lane >> 4, l16 = lane & 15;
    const int wn = wv * 32;

    __shared__ __attribute__((aligned(16))) u16 sA[8 * 64 * 40];
    float* sE = (float*)sA;  // epilogue reuse: 16 x 268 f32
    __shared__ float sMean[16], sRstd[16];
    __shared__ float sG[256], sBl[256];

    const int row = t >> 5;         // 0..15 (epilogue mapping)
    const int colb = (t & 31) * 8;  // 0..248

    // ---- T14 prefetch: res rows for this block's epilogue (issue-early) ----
    float4 rpre[4][2];
#pragma unroll
    for (int cch = 0; cch < 4; cch++) {
        const float* rp = res + (size_t)(m0 + cch * 16 + row) * 256 + colb;
#pragma unroll
        for (int q = 0; q < 2; q++) rpre[cch][q] = *(const float4*)(rp + q * 4);
    }

    if (t < 256) {
        sG[t] = lng[t];
        sBl[t] = lnb[t];
    }

    // ---- stage A = 3-tap neighbor mean (edge-replicate per batch) ----
#pragma unroll
    for (int q = 0; q < 4; q++) {
        const int id = q * 512 + t;
        const int arow = id >> 5;      // 0..63
        const int c8 = (id & 31) * 8;  // 0..248
        const int ks = c8 >> 5;
        const int kc = c8 & 31;
        const int gr = m0 + arow;
        const int rm = ((gr & (TT - 1)) == 0) ? gr : gr - 1;
        const int rp = (((gr + 1) & (TT - 1)) == 0) ? gr : gr + 1;
        float v0[8], v1[8], v2[8], o[8];
        unpack8(*(const uint4*)(A + (size_t)rm * 256 + c8), v0);
        unpack8(*(const uint4*)(A + (size_t)gr * 256 + c8), v1);
        unpack8(*(const uint4*)(A + (size_t)rp * 256 + c8), v2);
#pragma unroll
        for (int e = 0; e < 8; e++)
            o[e] = (v0[e] + v1[e] + v2[e]) * (1.0f / 3.0f);
        *(uint4*)(sA + (ks * 64 + arow) * 40 + kc) = pack8(o);
    }

    f32x4 acc[4][2];
#pragma unroll
    for (int i = 0; i < 4; i++)
#pragma unroll
        for (int j = 0; j < 2; j++) acc[i][j] = (f32x4){0.f, 0.f, 0.f, 0.f};

    __syncthreads();

    // ---- K-loop: no barriers; B straight from L2; 32 N-cols per wave ----
#pragma unroll
    for (int ks = 0; ks < 8; ks++) {
        bf16x8 bfr[2], af[4];
#pragma unroll
        for (int j = 0; j < 2; j++)
            bfr[j] = *(const bf16x8*)(Wt + (size_t)(wn + j * 16 + l16) * 256 +
                                      ks * 32 + quad * 8);
#pragma unroll
        for (int i = 0; i < 4; i++)
            af[i] = *(const bf16x8*)(sA + (ks * 64 + i * 16 + l16) * 40 +
                                     quad * 8);
#pragma unroll
        for (int i = 0; i < 4; i++)
#pragma unroll
            for (int j = 0; j < 2; j++)
                acc[i][j] = __builtin_amdgcn_mfma_f32_16x16x32_bf16(
                    af[i], bfr[j], acc[i][j], 0, 0, 0);
    }

    // ---- epilogue: res(prefetched) + bias add, fp32 store, LN bf16 store ----
    float bvl[2];
#pragma unroll
    for (int j = 0; j < 2; j++) bvl[j] = bias[wn + j * 16 + l16];

    for (int cch = 0; cch < 4; cch++) {
        const int gr = m0 + cch * 16 + row;
        __syncthreads();  // guard sE/sA reuse + prior chunk reads
        {
            float* sp = sE + row * 268 + colb;
#pragma unroll
            for (int q = 0; q < 2; q++) *(float4*)(sp + q * 4) = rpre[cch][q];
        }
        __syncthreads();
#pragma unroll
        for (int j = 0; j < 2; j++) {
#pragma unroll
            for (int rr = 0; rr < 4; rr++) {
                const int rl = quad * 4 + rr;
                const int ad = rl * 268 + wn + j * 16 + l16;
                sE[ad] += acc[cch][j][rr] + bvl[j];
            }
        }
        __syncthreads();
#pragma unroll
        for (int r4 = 0; r4 < 2; r4++) {
            const int rl = wv * 2 + r4;
            const float4 vv = *(const float4*)(sE + rl * 268 + lane * 4);
            float s = vv.x + vv.y + vv.z + vv.w;
            float ss = vv.x * vv.x + vv.y * vv.y + vv.z * vv.z + vv.w * vv.w;
            for (int m = 1; m < 64; m <<= 1) {
                s += __shfl_xor(s, m);
                ss += __shfl_xor(ss, m);
            }
            if (lane == 0) {
                const float mean = s * (1.0f / 256.0f);
                const float var = ss * (1.0f / 256.0f) - mean * mean;
                sMean[rl] = mean;
                sRstd[rl] = rsqrtf(fmaxf(var, 0.f) + 1e-5f);
            }
        }
        __syncthreads();
        const float* sp = sE + row * 268 + colb;
        {
            float* op = outf + (size_t)gr * 256 + colb;
#pragma unroll
            for (int q = 0; q < 2; q++)
                *(float4*)(op + q * 4) = *(const float4*)(sp + q * 4);
        }
        {
            const float m = sMean[row], rs = sRstd[row];
            float h[8];
#pragma unroll
            for (int e = 0; e < 8; e++)
                h[e] = (sp[e] - m) * rs * sG[colb + e] + sBl[colb + e];
            u16* hp = hout + (size_t)gr * 256 + colb;
            *(uint4*)hp = pack8(h);
        }
    }
}

// ---------------------------------------------------------------------------
// k_ffn: out = res + gelu(A@W1+b1)@W2 + b2, 512 threads / 8 waves.
// r12 = r9 body (proven 99.4 µs; r11's barrier-cut + scalar epilogue
// regressed to 143 and is reverted) + T14 res-prefetch: the epilogue's res
// loads were the kernel TAIL; issue them at entry into 32 VGPR (block-
// exclusive rows -> early read safe), epilogue stores them to sE.
// LDS: sA (stride 36) 36864 + sT (stride 132) 16896 = 53760 B. lb(512,4);
// VGPR 64 -> ~96, under the 128 cap (no spill risk).
// ---------------------------------------------------------------------------
__global__ __launch_bounds__(512, 4) void k_ffn(
    const u16* __restrict__ A,    // [NTOK][256] bf16 (h3)
    const u16* __restrict__ W1T,  // [512][256] bf16
    const float* __restrict__ b1, // [512]
    const u16* __restrict__ W2T,  // [256][512] bf16
    const float* __restrict__ b2, // [256]
    const float* res,             // [NTOK][256] fp32 (r2) — may alias out
    float* out) {
    const int m0 = blockIdx.x * 64;
    const int t = threadIdx.x;
    const int lane = t & 63, wv = t >> 6;
    const int quad = lane >> 4, l16 = lane & 15;
    const int wn = wv * 32;

    __shared__ __attribute__((aligned(16))) u16 sA[8 * 64 * 36];  // 36864 B
    __shared__ __attribute__((aligned(16))) u16 sT[64 * 132];     // 16896 B
    float* sE = (float*)sA;  // epilogue reuse: 16 x 268 f32 (17152 B)

    const int row = t >> 5;         // 0..15 (epilogue mapping)
    const int colb = (t & 31) * 8;  // 0..248

    // ---- T14 prefetch: res rows for this block's epilogue (issue-early) ----
    float4 rpre[4][2];
#pragma unroll
    for (int cch = 0; cch < 4; cch++) {
        const float* rp = res + (size_t)(m0 + cch * 16 + row) * 256 + colb;
#pragma unroll
        for (int q = 0; q < 2; q++) rpre[cch][q] = *(const float4*)(rp + q * 4);
    }

    // ---- stage A tile (64 x 256 bf16 = 2048 uint4, coalesced) ----
#pragma unroll
    for (int q = 0; q < 4; q++) {
        const int id = q * 512 + t;
        const int arow = id >> 5;        // 0..63
        const int c8 = (id & 31) * 8;    // 0..248
        const int ks = c8 >> 5;          // 0..7
        const int kc = c8 & 31;          // 0,8,16,24
        *(uint4*)(sA + (ks * 64 + arow) * 36 + kc) =
            *(const uint4*)(A + (size_t)(m0 + arow) * 256 + c8);
    }

    f32x4 acc2[4][2];
#pragma unroll
    for (int i = 0; i < 4; i++)
#pragma unroll
        for (int jj = 0; jj < 2; jj++) acc2[i][jj] = (f32x4){0.f, 0.f, 0.f, 0.f};

    __syncthreads();

    for (int j4 = 0; j4 < 4; j4++) {
        // ---- GEMM1: wave wv computes T1[:, j4*128 + wv*16 .. +15] ----
        const int n1 = j4 * 128 + wv * 16 + l16;
        bf16x8 bw[8];
#pragma unroll
        for (int ks = 0; ks < 8; ks++)
            bw[ks] = *(const bf16x8*)(W1T + (size_t)n1 * 256 + ks * 32 + quad * 8);
        f32x4 acc1[4];
#pragma unroll
        for (int i = 0; i < 4; i++) acc1[i] = (f32x4){0.f, 0.f, 0.f, 0.f};
#pragma unroll
        for (int ks = 0; ks < 8; ks++) {
#pragma unroll
            for (int i = 0; i < 4; i++) {
                const bf16x8 af = *(const bf16x8*)(
                    sA + (ks * 64 + i * 16 + l16) * 36 + quad * 8);
                acc1[i] = __builtin_amdgcn_mfma_f32_16x16x32_bf16(
                    af, bw[ks], acc1[i], 0, 0, 0);
            }
        }
        // ---- prefetch W2 fragments for this chunk (independent of sT) ----
        bf16x8 bw2[8];
#pragma unroll
        for (int kh = 0; kh < 4; kh++)
#pragma unroll
            for (int jj = 0; jj < 2; jj++)
                bw2[kh * 2 + jj] = *(const bf16x8*)(
                    W2T + (size_t)(wn + jj * 16 + l16) * 512 + j4 * 128 +
                    kh * 32 + quad * 8);
        // ---- bias + exact GELU, pack to sT (row quad*4+rr, col wv*16+l16) --
        const float b1l = b1[n1];
#pragma unroll
        for (int i = 0; i < 4; i++)
#pragma unroll
            for (int rr = 0; rr < 4; rr++) {
                float v = acc1[i][rr] + b1l;
                v = 0.5f * v * (1.0f + erff(v * 0.70710678118654752f));
                sT[(i * 16 + quad * 4 + rr) * 132 + wv * 16 + l16] = f2bf(v);
            }
        __syncthreads();
        // ---- GEMM2: acc2 += T1chunk @ W2[j4*128 .. +127][:] ----
#pragma unroll
        for (int kh = 0; kh < 4; kh++) {
#pragma unroll
            for (int i = 0; i < 4; i++) {
                const bf16x8 af = *(const bf16x8*)(
                    sT + (i * 16 + l16) * 132 + kh * 32 + quad * 8);
#pragma unroll
                for (int jj = 0; jj < 2; jj++)
                    acc2[i][jj] = __builtin_amdgcn_mfma_f32_16x16x32_bf16(
                        af, bw2[kh * 2 + jj], acc2[i][jj], 0, 0, 0);
            }
        }
        __syncthreads();  // sT (and, after j4=3, sA) free for reuse
    }

    // ---- epilogue: out = acc2 + b2 + res(prefetched), 4 chunks of 16 rows --
    float bvl[2];
#pragma unroll
    for (int jj = 0; jj < 2; jj++) bvl[jj] = b2[wn + jj * 16 + l16];
    for (int cch = 0; cch < 4; cch++) {
        const int gr = m0 + cch * 16 + row;
        __syncthreads();
        {
            float* sp = sE + row * 268 + colb;
#pragma unroll
            for (int q = 0; q < 2; q++) *(float4*)(sp + q * 4) = rpre[cch][q];
        }
        __syncthreads();
#pragma unroll
        for (int jj = 0; jj < 2; jj++)
#pragma unroll
            for (int rr = 0; rr < 4; rr++) {
                const int ad = (quad * 4 + rr) * 268 + wn + jj * 16 + l16;
                sE[ad] += acc2[cch][jj][rr] + bvl[jj];
            }
        __syncthreads();
        {
            float* op = out + (size_t)gr * 256 + colb;
            const float* sp = sE + row * 268 + colb;
#pragma unroll
            for (int q = 0; q < 2; q++)
                *(float4*)(op + q * 4) = *(const float4*)(sp + q * 4);
        }
    }
}

// ---------------------------------------------------------------------------
extern "C" void kernel_launch(void* const* d_in, const int* in_sizes, int n_in,
                              void* d_out, int out_size, void* d_ws,
                              size_t ws_size, hipStream_t stream) {
    const float* x = (const float*)d_in[0];
    const float* n1g = (const float*)d_in[1];
    const float* n1b = (const float*)d_in[2];
    const float* n2g = (const float*)d_in[3];
    const float* n2b = (const float*)d_in[4];
    const float* n3g = (const float*)d_in[5];
    const float* n3b = (const float*)d_in[6];
    const float* tWv = (const float*)d_in[7];
    const float* tbv = (const float*)d_in[8];
    const float* tWo = (const float*)d_in[9];
    const float* tbo = (const float*)d_in[10];
    const float* aWv = (const float*)d_in[11];
    const float* abv = (const float*)d_in[12];
    const float* aWo = (const float*)d_in[13];
    const float* abo = (const float*)d_in[14];
    const float* fW1 = (const float*)d_in[15];
    const float* fb1 = (const float*)d_in[16];
    const float* fW2 = (const float*)d_in[17];
    const float* fb2 = (const float*)d_in[18];
    float* outp = (float*)d_out;

    u16* wq = (u16*)d_ws;
    u16* tWoT = wq;                      //  65536  [256][256]
    u16* aWoT = wq + 65536;              //  65536
    u16* fW1T = wq + 131072;             // 131072  [512][256]
    u16* fW2T = wq + 262144;             // 131072  [256][512]
    u16* WcT1 = wq + 393216;             //  65536
    u16* WcT2 = wq + 458752;             //  65536
    u16* tWvB = wq + 524288;             //  65536
    u16* aWvB = wq + 589824;             //  65536
    float* bc1 = (float*)(wq + 655360);  //  256 fp32
    float* bc2 = (float*)(wq + 655872);  //  256 fp32
    const size_t W_ELEMS = 656384;
    const size_t SLOT = (size_t)NTOK * 256;
    u16* slot1 = wq + W_ELEMS;
    u16* slot2 = slot1 + SLOT;

    const size_t need = (W_ELEMS + 3 * SLOT) * 2;  // ~97.3 MB (fits: r5)
    if (ws_size < need) {
        k_diag<<<dim3(NTOK), 256, 0, stream>>>(outp,
                                               512.0f + (float)(ws_size >> 20));
        return;
    }

    // --- weight prep (2 launches) ---
    k_transpose<<<dim3(16, 16, 8), 256, 0, stream>>>(
        tWo, aWo, fW1, fW2, tWv, aWv, tWoT, aWoT, fW1T, fW2T, tWvB, aWvB,
        tbv, tbo, abv, abo, bc1, bc2);
    k_gemm_prep<<<dim3(2, 2, 2), 256, 0, stream>>>(tWoT, tWvB, WcT1, aWoT,
                                                   aWvB, WcT2);

    // P1+P2 fused: r1 = x + temporal(LN1(x))@Wc1 + bc1 -> d_out (fp32);
    //              h2 = LN2(r1) -> slot2 (bf16)
    k_p12<<<dim3(TT / 64, BB), 512, 0, stream>>>(x, n1g, n1b, WcT1, bc1, outp,
                                                 n2g, n2b, slot2);

    // P3: r2 = r1 + nbr(h2)@Wc2 + bc2 -> d_out (in-place); h3 = LN3 -> slot1
    k_mega2<<<dim3(NTOK / 64), 512, 0, stream>>>(slot2, WcT2, bc2, outp, outp,
                                                 n3g, n3b, slot1);

    // P4+P5+P6 fused: out = r2 + gelu(h3@W1+b1)@W2 + b2 (in-place residual)
    k_ffn<<<dim3(NTOK / 64), 512, 0, stream>>>(slot1, fW1T, fb1, fW2T, fb2,
                                               outp, outp);
}

// Round 13
// 334.464 us; speedup vs baseline: 1.1387x; 1.1100x over previous
//
#include <hip/hip_runtime.h>
#include <cstdint>
#include <cstddef>

// Problem constants (B=8, T=8192, D=256, H=16, K=3, decay=0.9, eps=1e-5)
// I/O dtype: fp32. Internal staging: bf16 (MFMA). ws >= 97.3 MB (confirmed r5).
// r13 = exact restore of the r6 configuration (session best, 337.5 µs).
#define TT 8192
#define BB 8
#define DD 256
#define NTOK (BB * TT)

typedef unsigned short u16;
typedef unsigned int u32;

typedef __attribute__((ext_vector_type(8))) short bf16x8;
typedef __attribute__((ext_vector_type(4))) float f32x4;

__device__ __forceinline__ float bf2f(u16 u) {
    u32 v = ((u32)u) << 16;
    float f;
    __builtin_memcpy(&f, &v, 4);
    return f;
}

__device__ __forceinline__ u16 f2bf(float f) {
    u32 v;
    __builtin_memcpy(&v, &f, 4);
    u32 r = (v + 0x7FFFu + ((v >> 16) & 1u)) >> 16;  // RNE
    return (u16)r;
}

__device__ __forceinline__ uint2 pack4(const float* v) {
    uint2 p;
    p.x = (u32)f2bf(v[0]) | ((u32)f2bf(v[1]) << 16);
    p.y = (u32)f2bf(v[2]) | ((u32)f2bf(v[3]) << 16);
    return p;
}

__device__ __forceinline__ void unpack4(uint2 p, float* v) {
    v[0] = bf2f((u16)(p.x & 0xFFFFu));
    v[1] = bf2f((u16)(p.x >> 16));
    v[2] = bf2f((u16)(p.y & 0xFFFFu));
    v[3] = bf2f((u16)(p.y >> 16));
}

__device__ __forceinline__ uint4 pack8(const float* v) {
    uint4 p;
    p.x = (u32)f2bf(v[0]) | ((u32)f2bf(v[1]) << 16);
    p.y = (u32)f2bf(v[2]) | ((u32)f2bf(v[3]) << 16);
    p.z = (u32)f2bf(v[4]) | ((u32)f2bf(v[5]) << 16);
    p.w = (u32)f2bf(v[6]) | ((u32)f2bf(v[7]) << 16);
    return p;
}

__device__ __forceinline__ void unpack8(uint4 p, float* v) {
    v[0] = bf2f((u16)(p.x & 0xFFFFu));
    v[1] = bf2f((u16)(p.x >> 16));
    v[2] = bf2f((u16)(p.y & 0xFFFFu));
    v[3] = bf2f((u16)(p.y >> 16));
    v[4] = bf2f((u16)(p.z & 0xFFFFu));
    v[5] = bf2f((u16)(p.z >> 16));
    v[6] = bf2f((u16)(p.w & 0xFFFFu));
    v[7] = bf2f((u16)(p.w >> 16));
}

// ---------------------------------------------------------------------------
__global__ __launch_bounds__(256) void k_diag(float* out, float code) {
    out[(size_t)blockIdx.x * 256 + threadIdx.x] = code;
}

// ---------------------------------------------------------------------------
// Weight transpose/convert fp32 -> bf16 (proven) + bias compose folded in
// (z=6,7).
// ---------------------------------------------------------------------------
__global__ __launch_bounds__(256) void k_transpose(
    const float* s0, const float* s1, const float* s2, const float* s3,
    const float* s4, const float* s5,
    u16* d0, u16* d1, u16* d2, u16* d3, u16* d4, u16* d5,
    const float* tbv, const float* tbo, const float* abv, const float* abo,
    float* bc1, float* bc2) {
    const int z = blockIdx.z;
    if (z >= 6) {  // bias compose: bc[n] = sum_j bv[j]*Wo[j][n] + bo[n]
        if (blockIdx.x || blockIdx.y) return;
        const float* bv = (z == 7) ? abv : tbv;
        const float* Wo = (z == 7) ? s1 : s0;  // aWo : tWo (fp32 sources)
        const float* bo = (z == 7) ? abo : tbo;
        float* bc = (z == 7) ? bc2 : bc1;
        const int n = threadIdx.x;
        float s = bo[n];
        for (int j = 0; j < 256; j++) s += bv[j] * Wo[j * 256 + n];
        bc[n] = s;
        return;
    }
    const float* src;
    u16* dst;
    int K, N, tr;
    switch (z) {
        case 0: src = s0; dst = d0; K = 256; N = 256; tr = 1; break;
        case 1: src = s1; dst = d1; K = 256; N = 256; tr = 1; break;
        case 2: src = s2; dst = d2; K = 256; N = 512; tr = 1; break;
        case 3: src = s3; dst = d3; K = 512; N = 256; tr = 1; break;
        case 4: src = s4; dst = d4; K = 256; N = 256; tr = 0; break;
        default: src = s5; dst = d5; K = 256; N = 256; tr = 0; break;
    }
    const int nb = blockIdx.x * 32, kb = blockIdx.y * 32;
    if (nb >= N || kb >= K) return;
    const int tx = threadIdx.x & 31, ty = threadIdx.x >> 5;
    if (!tr) {
        for (int i = ty; i < 32; i += 8)
            dst[(size_t)(kb + i) * N + nb + tx] =
                f2bf(src[(size_t)(kb + i) * N + nb + tx]);
        return;
    }
    __shared__ u16 tile[32][33];
    for (int i = ty; i < 32; i += 8)
        tile[i][tx] = f2bf(src[(size_t)(kb + i) * N + nb + tx]);
    __syncthreads();
    for (int i = ty; i < 32; i += 8)
        dst[(size_t)(nb + i) * K + kb + tx] = tile[tx][i];
}

// ---------------------------------------------------------------------------
// Prep-only MFMA GEMM (weight composition, 256x256), both sets in one launch.
// ---------------------------------------------------------------------------
__global__ __launch_bounds__(256) void k_gemm_prep(
    const u16* __restrict__ A0, const u16* __restrict__ B0, u16* O0,
    const u16* __restrict__ A1, const u16* __restrict__ B1, u16* O1) {
    const u16* A = blockIdx.z ? A1 : A0;
    const u16* Wt = blockIdx.z ? B1 : B0;
    u16* out = blockIdx.z ? O1 : O0;
    const int m0 = blockIdx.y * 128;
    const int n0 = blockIdx.x * 128;
    const int tid = threadIdx.x;
    const int wv = tid >> 6, lane = tid & 63;
    const int quad = lane >> 4, l16 = lane & 15;
    const int wm = (wv >> 1) * 64, wn = (wv & 1) * 64;

    __shared__ u16 lA[128 * 40];
    __shared__ u16 lB[128 * 40];

    f32x4 acc[4][4];
#pragma unroll
    for (int i = 0; i < 4; i++)
#pragma unroll
        for (int j = 0; j < 4; j++) acc[i][j] = (f32x4){0.f, 0.f, 0.f, 0.f};

    const int r = tid >> 2;
    const int c = tid & 3;

    for (int k0 = 0; k0 < 256; k0 += 32) {
        __syncthreads();
        {
            const uint4 a0 = *(const uint4*)(A + (size_t)(m0 + r) * 256 + k0 + c * 8);
            const uint4 a1 = *(const uint4*)(A + (size_t)(m0 + r + 64) * 256 + k0 + c * 8);
            const uint4 b0 = *(const uint4*)(Wt + (size_t)(n0 + r) * 256 + k0 + c * 8);
            const uint4 b1 = *(const uint4*)(Wt + (size_t)(n0 + r + 64) * 256 + k0 + c * 8);
            *(uint4*)(lA + r * 40 + c * 8) = a0;
            *(uint4*)(lA + (r + 64) * 40 + c * 8) = a1;
            *(uint4*)(lB + r * 40 + c * 8) = b0;
            *(uint4*)(lB + (r + 64) * 40 + c * 8) = b1;
        }
        __syncthreads();
        bf16x8 af[4], bfr[4];
#pragma unroll
        for (int i = 0; i < 4; i++)
            af[i] = *(const bf16x8*)(lA + (wm + i * 16 + l16) * 40 + quad * 8);
#pragma unroll
        for (int j = 0; j < 4; j++)
            bfr[j] = *(const bf16x8*)(lB + (wn + j * 16 + l16) * 40 + quad * 8);
#pragma unroll
        for (int i = 0; i < 4; i++)
#pragma unroll
            for (int j = 0; j < 4; j++)
                acc[i][j] = __builtin_amdgcn_mfma_f32_16x16x32_bf16(
                    af[i], bfr[j], acc[i][j], 0, 0, 0);
    }

#pragma unroll
    for (int i = 0; i < 4; i++) {
        const int rowb = m0 + wm + i * 16 + quad * 4;
#pragma unroll
        for (int j = 0; j < 4; j++) {
            const int col = n0 + wn + j * 16 + l16;
#pragma unroll
            for (int rr = 0; rr < 4; rr++)
                out[(size_t)(rowb + rr) * 256 + col] = f2bf(acc[i][j][rr]);
        }
    }
}

// ---------------------------------------------------------------------------
// k_p12: fused P1+P2, 512 threads / 8 waves (r6-proven).
//   r1 = x + temporal(LN1(x))@Wc1 + bc1 -> outf (fp32)
//   h2 = LN2(r1)*g+b -> hout (bf16)
// ---------------------------------------------------------------------------
__global__ __launch_bounds__(512, 4) void k_p12(
    const float* __restrict__ x, const float* __restrict__ n1g,
    const float* __restrict__ n1b, const u16* __restrict__ Wt,
    const float* __restrict__ bias, float* outf,
    const float* __restrict__ lng, const float* __restrict__ lnb,
    u16* __restrict__ hout) {
    const int b = blockIdx.y;
    const int t0 = blockIdx.x * 64;
    const size_t base = (size_t)b * TT;
    const int t = threadIdx.x;
    const int lane = t & 63, wv = t >> 6;
    const int quad = lane >> 4, l16 = lane & 15;
    const int wn = wv * 32;

    __shared__ __attribute__((aligned(16))) u16 hl[79 * 256];   // 40448 B
    __shared__ __attribute__((aligned(16))) u16 sAg[64 * 264];  // 33792 B
    float* sE = (float*)hl;  // epilogue reuse (16 x 268 f32 = 17152 B)
    __shared__ float sMean[16], sRstd[16];
    __shared__ float sG[256], sBl[256];

    if (t < 256) {
        sG[t] = lng[t];
        sBl[t] = lnb[t];
    }

    // ---- Phase A: LN1 rows into hl (proven body; 8 waves stripe rows) ----
    const int d4 = lane * 4;
    {
        const float4 gv = *(const float4*)(n1g + d4);
        const float4 bv = *(const float4*)(n1b + d4);
        for (int i = wv; i < 79; i += 8) {
            const int tt = t0 + i - 15;
            if (tt < 0) {
                *(uint2*)(hl + i * 256 + d4) = make_uint2(0u, 0u);
                continue;
            }
            const float4 v = *(const float4*)(x + (base + tt) * DD + d4);
            float s = v.x + v.y + v.z + v.w;
            float ss = v.x * v.x + v.y * v.y + v.z * v.z + v.w * v.w;
            for (int m = 1; m < 64; m <<= 1) {
                s += __shfl_xor(s, m);
                ss += __shfl_xor(ss, m);
            }
            const float mean = s * (1.0f / 256.0f);
            const float var = ss * (1.0f / 256.0f) - mean * mean;
            const float rs = rsqrtf(fmaxf(var, 0.f) + 1e-5f);
            float h[4] = {(v.x - mean) * rs * gv.x + bv.x,
                          (v.y - mean) * rs * gv.y + bv.y,
                          (v.z - mean) * rs * gv.z + bv.z,
                          (v.w - mean) * rs * gv.w + bv.w};
            *(uint2*)(hl + i * 256 + d4) = pack4(h);
        }
    }
    __syncthreads();

    // ---- Phase B: sliding-window temporal agg -> sAg (8 rows per wave) ----
    {
        float p = 1.f, s = 0.f, w15 = 1.f;
        for (int j = 0; j < 16; j++) {
            s += p;
            if (j == 15) w15 = p;
            p *= 0.9f;
        }
        const float c = 1.f / s;
        const float inv09 = 1.0f / 0.9f;
        const int tg = wv * 8;
        float g[4] = {0.f, 0.f, 0.f, 0.f};
        float pw = 1.f;
        for (int j = 0; j < 16; j++) {
            float h[4];
            unpack4(*(const uint2*)(hl + (tg + j) * 256 + d4), h);
            g[0] += pw * h[0];
            g[1] += pw * h[1];
            g[2] += pw * h[2];
            g[3] += pw * h[3];
            pw *= 0.9f;
        }
        {
            float a[4] = {c * g[0], c * g[1], c * g[2], c * g[3]};
            *(uint2*)(sAg + tg * 264 + d4) = pack4(a);
        }
        for (int ot = tg + 1; ot < tg + 8; ++ot) {
            float hold[4], hnew[4];
            unpack4(*(const uint2*)(hl + (ot - 1) * 256 + d4), hold);
            unpack4(*(const uint2*)(hl + (ot + 15) * 256 + d4), hnew);
#pragma unroll
            for (int e = 0; e < 4; e++)
                g[e] = (g[e] - hold[e]) * inv09 + w15 * hnew[e];
            float a[4] = {c * g[0], c * g[1], c * g[2], c * g[3]};
            *(uint2*)(sAg + ot * 264 + d4) = pack4(a);
        }
    }
    __syncthreads();

    // ---- Phase C: GEMM, barrier-free K-loop; 32 N-cols per wave ----
    f32x4 acc[4][2];
#pragma unroll
    for (int i = 0; i < 4; i++)
#pragma unroll
        for (int j = 0; j < 2; j++) acc[i][j] = (f32x4){0.f, 0.f, 0.f, 0.f};
#pragma unroll
    for (int ks = 0; ks < 8; ks++) {
        bf16x8 bfr[2], af[4];
#pragma unroll
        for (int j = 0; j < 2; j++)
            bfr[j] = *(const bf16x8*)(Wt + (size_t)(wn + j * 16 + l16) * 256 +
                                      ks * 32 + quad * 8);
#pragma unroll
        for (int i = 0; i < 4; i++)
            af[i] = *(const bf16x8*)(sAg + (i * 16 + l16) * 264 + ks * 32 +
                                     quad * 8);
#pragma unroll
        for (int i = 0; i < 4; i++)
#pragma unroll
            for (int j = 0; j < 2; j++)
                acc[i][j] = __builtin_amdgcn_mfma_f32_16x16x32_bf16(
                    af[i], bfr[j], acc[i][j], 0, 0, 0);
    }

    // ---- Phase D: epilogue (res=x, fp32 out, LN2 bf16 out) ----
    float bvl[2];
#pragma unroll
    for (int j = 0; j < 2; j++) bvl[j] = bias[wn + j * 16 + l16];

    const int row = t >> 5;         // 0..15
    const int colb = (t & 31) * 8;  // 0..248
    for (int cch = 0; cch < 4; cch++) {
        const size_t grow = base + t0 + cch * 16 + row;
        __syncthreads();  // guard sE overlay of hl + prior chunk reads
        {
            const float* rp = x + grow * 256 + colb;
            float* sp = sE + row * 268 + colb;
#pragma unroll
            for (int q = 0; q < 2; q++)
                *(float4*)(sp + q * 4) = *(const float4*)(rp + q * 4);
        }
        __syncthreads();
#pragma unroll
        for (int j = 0; j < 2; j++) {
#pragma unroll
            for (int rr = 0; rr < 4; rr++) {
                const int rl = quad * 4 + rr;
                const int ad = rl * 268 + wn + j * 16 + l16;
                sE[ad] += acc[cch][j][rr] + bvl[j];
            }
        }
        __syncthreads();
#pragma unroll
        for (int r4 = 0; r4 < 2; r4++) {
            const int rl = wv * 2 + r4;
            const float4 vv = *(const float4*)(sE + rl * 268 + lane * 4);
            float s = vv.x + vv.y + vv.z + vv.w;
            float ss = vv.x * vv.x + vv.y * vv.y + vv.z * vv.z + vv.w * vv.w;
            for (int m = 1; m < 64; m <<= 1) {
                s += __shfl_xor(s, m);
                ss += __shfl_xor(ss, m);
            }
            if (lane == 0) {
                const float mean = s * (1.0f / 256.0f);
                const float var = ss * (1.0f / 256.0f) - mean * mean;
                sMean[rl] = mean;
                sRstd[rl] = rsqrtf(fmaxf(var, 0.f) + 1e-5f);
            }
        }
        __syncthreads();
        const float* sp = sE + row * 268 + colb;
        {
            float* op = outf + grow * 256 + colb;
#pragma unroll
            for (int q = 0; q < 2; q++)
                *(float4*)(op + q * 4) = *(const float4*)(sp + q * 4);
        }
        {
            const float m = sMean[row], rs = sRstd[row];
            float h[8];
#pragma unroll
            for (int e = 0; e < 8; e++)
                h[e] = (sp[e] - m) * rs * sG[colb + e] + sBl[colb + e];
            u16* hp = hout + grow * 256 + colb;
            *(uint4*)hp = pack8(h);
        }
    }
}

// ---------------------------------------------------------------------------
// k_mega2: P3 (3-tap neighbor GEMM + residual + LN3 out), 512 threads
// (r6-proven exact body, lb(512,4)).
// ---------------------------------------------------------------------------
__global__ __launch_bounds__(512, 4) void k_mega2(
    const u16* __restrict__ A,      // [NTOK][256] bf16 (h2)
    const u16* __restrict__ Wt,     // [256][256] bf16 (N-major)
    const float* __restrict__ bias, // [256] composed
    const float* res,               // [NTOK][256] fp32 (may alias outf)
    float* outf,                    // [NTOK][256] fp32
    const float* __restrict__ lng, const float* __restrict__ lnb,
    u16* __restrict__ hout) {       // [NTOK][256] bf16 LN output
    const int m0 = blockIdx.x * 64;
    const int t = threadIdx.x;
    const int lane = t & 63, wv = t >> 6;
    const int quad = lane >> 4, l16 = lane & 15;
    const int wn = wv * 32;

    __shared__ __attribute__((aligned(16))) u16 sA[8 * 64 * 40];
    float* sE = (float*)sA;  // epilogue reuse: 16 x 268 f32
    __shared__ float sMean[16], sRstd[16];
    __shared__ float sG[256], sBl[256];

    if (t < 256) {
        sG[t] = lng[t];
        sBl[t] = lnb[t];
    }

    // ---- stage A = 3-tap neighbor mean (edge-replicate per batch) ----
#pragma unroll
    for (int q = 0; q < 4; q++) {
        const int id = q * 512 + t;
        const int arow = id >> 5;      // 0..63
        const int c8 = (id & 31) * 8;  // 0..248
        const int ks = c8 >> 5;
        const int kc = c8 & 31;
        const int gr = m0 + arow;
        const int rm = ((gr & (TT - 1)) == 0) ? gr : gr - 1;
        const int rp = (((gr + 1) & (TT - 1)) == 0) ? gr : gr + 1;
        float v0[8], v1[8], v2[8], o[8];
        unpack8(*(const uint4*)(A + (size_t)rm * 256 + c8), v0);
        unpack8(*(const uint4*)(A + (size_t)gr * 256 + c8), v1);
        unpack8(*(const uint4*)(A + (size_t)rp * 256 + c8), v2);
#pragma unroll
        for (int e = 0; e < 8; e++)
            o[e] = (v0[e] + v1[e] + v2[e]) * (1.0f / 3.0f);
        *(uint4*)(sA + (ks * 64 + arow) * 40 + kc) = pack8(o);
    }

    f32x4 acc[4][2];
#pragma unroll
    for (int i = 0; i < 4; i++)
#pragma unroll
        for (int j = 0; j < 2; j++) acc[i][j] = (f32x4){0.f, 0.f, 0.f, 0.f};

    __syncthreads();

    // ---- K-loop: no barriers; B straight from L2; 32 N-cols per wave ----
#pragma unroll
    for (int ks = 0; ks < 8; ks++) {
        bf16x8 bfr[2], af[4];
#pragma unroll
        for (int j = 0; j < 2; j++)
            bfr[j] = *(const bf16x8*)(Wt + (size_t)(wn + j * 16 + l16) * 256 +
                                      ks * 32 + quad * 8);
#pragma unroll
        for (int i = 0; i < 4; i++)
            af[i] = *(const bf16x8*)(sA + (ks * 64 + i * 16 + l16) * 40 +
                                     quad * 8);
#pragma unroll
        for (int i = 0; i < 4; i++)
#pragma unroll
            for (int j = 0; j < 2; j++)
                acc[i][j] = __builtin_amdgcn_mfma_f32_16x16x32_bf16(
                    af[i], bfr[j], acc[i][j], 0, 0, 0);
    }

    // ---- epilogue: res + bias add, fp32 store, LN bf16 store ----
    float bvl[2];
#pragma unroll
    for (int j = 0; j < 2; j++) bvl[j] = bias[wn + j * 16 + l16];

    const int row = t >> 5;         // 0..15
    const int colb = (t & 31) * 8;  // 0..248
    for (int cch = 0; cch < 4; cch++) {
        const int gr = m0 + cch * 16 + row;
        __syncthreads();  // guard sE/sA reuse + prior chunk reads
        {
            const float* rp = res + (size_t)gr * 256 + colb;
            float* sp = sE + row * 268 + colb;
#pragma unroll
            for (int q = 0; q < 2; q++)
                *(float4*)(sp + q * 4) = *(const float4*)(rp + q * 4);
        }
        __syncthreads();
#pragma unroll
        for (int j = 0; j < 2; j++) {
#pragma unroll
            for (int rr = 0; rr < 4; rr++) {
                const int rl = quad * 4 + rr;
                const int ad = rl * 268 + wn + j * 16 + l16;
                sE[ad] += acc[cch][j][rr] + bvl[j];
            }
        }
        __syncthreads();
#pragma unroll
        for (int r4 = 0; r4 < 2; r4++) {
            const int rl = wv * 2 + r4;
            const float4 vv = *(const float4*)(sE + rl * 268 + lane * 4);
            float s = vv.x + vv.y + vv.z + vv.w;
            float ss = vv.x * vv.x + vv.y * vv.y + vv.z * vv.z + vv.w * vv.w;
            for (int m = 1; m < 64; m <<= 1) {
                s += __shfl_xor(s, m);
                ss += __shfl_xor(ss, m);
            }
            if (lane == 0) {
                const float mean = s * (1.0f / 256.0f);
                const float var = ss * (1.0f / 256.0f) - mean * mean;
                sMean[rl] = mean;
                sRstd[rl] = rsqrtf(fmaxf(var, 0.f) + 1e-5f);
            }
        }
        __syncthreads();
        const float* sp = sE + row * 268 + colb;
        {
            float* op = outf + (size_t)gr * 256 + colb;
#pragma unroll
            for (int q = 0; q < 2; q++)
                *(float4*)(op + q * 4) = *(const float4*)(sp + q * 4);
        }
        {
            const float m = sMean[row], rs = sRstd[row];
            float h[8];
#pragma unroll
            for (int e = 0; e < 8; e++)
                h[e] = (sp[e] - m) * rs * sG[colb + e] + sBl[colb + e];
            u16* hp = hout + (size_t)gr * 256 + colb;
            *(uint4*)hp = pack8(h);
        }
    }
}

// ---------------------------------------------------------------------------
// k_ffn: out = res + gelu(A@W1+b1)@W2 + b2, 512 threads / 8 waves
// (r6-proven exact body: sA stride 40, sT 64x136 single-buffer, bw2 prefetch
// after GEMM1, 4x16-row LDS epilogue; lb(512,4), VGPR 56, LDS 58368,
// measured 99.0 µs). Six later interventions (pipeline, LDS shrink,
// conflict fix, barrier cut, reg epilogue, res prefetch) were all null or
// negative — this is the empirical floor of this decomposition.
// ---------------------------------------------------------------------------
__global__ __launch_bounds__(512, 4) void k_ffn(
    const u16* __restrict__ A,    // [NTOK][256] bf16 (h3)
    const u16* __restrict__ W1T,  // [512][256] bf16
    const float* __restrict__ b1, // [512]
    const u16* __restrict__ W2T,  // [256][512] bf16
    const float* __restrict__ b2, // [256]
    const float* res,             // [NTOK][256] fp32 (r2) — may alias out
    float* out) {
    const int m0 = blockIdx.x * 64;
    const int t = threadIdx.x;
    const int lane = t & 63, wv = t >> 6;
    const int quad = lane >> 4, l16 = lane & 15;
    const int wn = wv * 32;

    __shared__ __attribute__((aligned(16))) u16 sA[8 * 64 * 40];  // 40960 B
    __shared__ __attribute__((aligned(16))) u16 sT[64 * 136];     // 17408 B
    float* sE = (float*)sA;  // epilogue reuse: 16 x 268 f32

    // ---- stage A tile (64 x 256 bf16 = 2048 uint4, coalesced) ----
#pragma unroll
    for (int q = 0; q < 4; q++) {
        const int id = q * 512 + t;
        const int arow = id >> 5;        // 0..63
        const int c8 = (id & 31) * 8;    // 0..248
        const int ks = c8 >> 5;          // 0..7
        const int kc = c8 & 31;          // 0,8,16,24
        *(uint4*)(sA + (ks * 64 + arow) * 40 + kc) =
            *(const uint4*)(A + (size_t)(m0 + arow) * 256 + c8);
    }

    f32x4 acc2[4][2];
#pragma unroll
    for (int i = 0; i < 4; i++)
#pragma unroll
        for (int jj = 0; jj < 2; jj++) acc2[i][jj] = (f32x4){0.f, 0.f, 0.f, 0.f};

    __syncthreads();

    for (int j4 = 0; j4 < 4; j4++) {
        // ---- GEMM1: wave wv computes T1[:, j4*128 + wv*16 .. +15] ----
        const int n1 = j4 * 128 + wv * 16 + l16;
        bf16x8 bw[8];
#pragma unroll
        for (int ks = 0; ks < 8; ks++)
            bw[ks] = *(const bf16x8*)(W1T + (size_t)n1 * 256 + ks * 32 + quad * 8);
        f32x4 acc1[4];
#pragma unroll
        for (int i = 0; i < 4; i++) acc1[i] = (f32x4){0.f, 0.f, 0.f, 0.f};
#pragma unroll
        for (int ks = 0; ks < 8; ks++) {
#pragma unroll
            for (int i = 0; i < 4; i++) {
                const bf16x8 af = *(const bf16x8*)(
                    sA + (ks * 64 + i * 16 + l16) * 40 + quad * 8);
                acc1[i] = __builtin_amdgcn_mfma_f32_16x16x32_bf16(
                    af, bw[ks], acc1[i], 0, 0, 0);
            }
        }
        // ---- prefetch W2 fragments for this chunk (independent of sT) ----
        bf16x8 bw2[8];
#pragma unroll
        for (int kh = 0; kh < 4; kh++)
#pragma unroll
            for (int jj = 0; jj < 2; jj++)
                bw2[kh * 2 + jj] = *(const bf16x8*)(
                    W2T + (size_t)(wn + jj * 16 + l16) * 512 + j4 * 128 +
                    kh * 32 + quad * 8);
        // ---- bias + exact GELU, pack to sT (row quad*4+rr, col wv*16+l16) --
        const float b1l = b1[n1];
#pragma unroll
        for (int i = 0; i < 4; i++)
#pragma unroll
            for (int rr = 0; rr < 4; rr++) {
                float v = acc1[i][rr] + b1l;
                v = 0.5f * v * (1.0f + erff(v * 0.70710678118654752f));
                sT[(i * 16 + quad * 4 + rr) * 136 + wv * 16 + l16] = f2bf(v);
            }
        __syncthreads();
        // ---- GEMM2: acc2 += T1chunk @ W2[j4*128 .. +127][:] ----
#pragma unroll
        for (int kh = 0; kh < 4; kh++) {
#pragma unroll
            for (int i = 0; i < 4; i++) {
                const bf16x8 af = *(const bf16x8*)(
                    sT + (i * 16 + l16) * 136 + kh * 32 + quad * 8);
#pragma unroll
                for (int jj = 0; jj < 2; jj++)
                    acc2[i][jj] = __builtin_amdgcn_mfma_f32_16x16x32_bf16(
                        af, bw2[kh * 2 + jj], acc2[i][jj], 0, 0, 0);
            }
        }
        __syncthreads();  // sT (and, after j4=3, sA) free for reuse
    }

    // ---- epilogue: out = acc2 + b2 + res, fp32, 4 chunks of 16 rows ----
    float bvl[2];
#pragma unroll
    for (int jj = 0; jj < 2; jj++) bvl[jj] = b2[wn + jj * 16 + l16];
    const int row = t >> 5;         // 0..15
    const int colb = (t & 31) * 8;  // 0..248
    for (int cch = 0; cch < 4; cch++) {
        const int gr = m0 + cch * 16 + row;
        __syncthreads();
        {
            const float* rp = res + (size_t)gr * 256 + colb;
            float* sp = sE + row * 268 + colb;
#pragma unroll
            for (int q = 0; q < 2; q++)
                *(float4*)(sp + q * 4) = *(const float4*)(rp + q * 4);
        }
        __syncthreads();
#pragma unroll
        for (int jj = 0; jj < 2; jj++)
#pragma unroll
            for (int rr = 0; rr < 4; rr++) {
                const int ad = (quad * 4 + rr) * 268 + wn + jj * 16 + l16;
                sE[ad] += acc2[cch][jj][rr] + bvl[jj];
            }
        __syncthreads();
        {
            float* op = out + (size_t)gr * 256 + colb;
            const float* sp = sE + row * 268 + colb;
#pragma unroll
            for (int q = 0; q < 2; q++)
                *(float4*)(op + q * 4) = *(const float4*)(sp + q * 4);
        }
    }
}

// ---------------------------------------------------------------------------
extern "C" void kernel_launch(void* const* d_in, const int* in_sizes, int n_in,
                              void* d_out, int out_size, void* d_ws,
                              size_t ws_size, hipStream_t stream) {
    const float* x = (const float*)d_in[0];
    const float* n1g = (const float*)d_in[1];
    const float* n1b = (const float*)d_in[2];
    const float* n2g = (const float*)d_in[3];
    const float* n2b = (const float*)d_in[4];
    const float* n3g = (const float*)d_in[5];
    const float* n3b = (const float*)d_in[6];
    const float* tWv = (const float*)d_in[7];
    const float* tbv = (const float*)d_in[8];
    const float* tWo = (const float*)d_in[9];
    const float* tbo = (const float*)d_in[10];
    const float* aWv = (const float*)d_in[11];
    const float* abv = (const float*)d_in[12];
    const float* aWo = (const float*)d_in[13];
    const float* abo = (const float*)d_in[14];
    const float* fW1 = (const float*)d_in[15];
    const float* fb1 = (const float*)d_in[16];
    const float* fW2 = (const float*)d_in[17];
    const float* fb2 = (const float*)d_in[18];
    float* outp = (float*)d_out;

    u16* wq = (u16*)d_ws;
    u16* tWoT = wq;                      //  65536  [256][256]
    u16* aWoT = wq + 65536;              //  65536
    u16* fW1T = wq + 131072;             // 131072  [512][256]
    u16* fW2T = wq + 262144;             // 131072  [256][512]
    u16* WcT1 = wq + 393216;             //  65536
    u16* WcT2 = wq + 458752;             //  65536
    u16* tWvB = wq + 524288;             //  65536
    u16* aWvB = wq + 589824;             //  65536
    float* bc1 = (float*)(wq + 655360);  //  256 fp32
    float* bc2 = (float*)(wq + 655872);  //  256 fp32
    const size_t W_ELEMS = 656384;
    const size_t SLOT = (size_t)NTOK * 256;
    u16* slot1 = wq + W_ELEMS;
    u16* slot2 = slot1 + SLOT;

    const size_t need = (W_ELEMS + 3 * SLOT) * 2;  // ~97.3 MB (fits: r5)
    if (ws_size < need) {
        k_diag<<<dim3(NTOK), 256, 0, stream>>>(outp,
                                               512.0f + (float)(ws_size >> 20));
        return;
    }

    // --- weight prep (2 launches) ---
    k_transpose<<<dim3(16, 16, 8), 256, 0, stream>>>(
        tWo, aWo, fW1, fW2, tWv, aWv, tWoT, aWoT, fW1T, fW2T, tWvB, aWvB,
        tbv, tbo, abv, abo, bc1, bc2);
    k_gemm_prep<<<dim3(2, 2, 2), 256, 0, stream>>>(tWoT, tWvB, WcT1, aWoT,
                                                   aWvB, WcT2);

    // P1+P2 fused: r1 = x + temporal(LN1(x))@Wc1 + bc1 -> d_out (fp32);
    //              h2 = LN2(r1) -> slot2 (bf16)
    k_p12<<<dim3(TT / 64, BB), 512, 0, stream>>>(x, n1g, n1b, WcT1, bc1, outp,
                                                 n2g, n2b, slot2);

    // P3: r2 = r1 + nbr(h2)@Wc2 + bc2 -> d_out (in-place); h3 = LN3 -> slot1
    k_mega2<<<dim3(NTOK / 64), 512, 0, stream>>>(slot2, WcT2, bc2, outp, outp,
                                                 n3g, n3b, slot1);

    // P4+P5+P6 fused: out = r2 + gelu(h3@W1+b1)@W2 + b2 (in-place residual)
    k_ffn<<<dim3(NTOK / 64), 512, 0, stream>>>(slot1, fW1T, fb1, fW2T, fb2,
                                               outp, outp);
}

// Round 15
// 334.013 us; speedup vs baseline: 1.1402x; 1.0014x over previous
//
#include <hip/hip_runtime.h>
#include <cstdint>
#include <cstddef>

// Problem constants (B=8, T=8192, D=256, H=16, K=3, decay=0.9, eps=1e-5)
// I/O dtype: fp32. Internal staging: bf16 (MFMA). ws >= 97.3 MB (confirmed r5).
// r15 = r14 resubmitted (infra flake; kernel audited correct):
// r13 (r6 configuration, session best 334.5 µs) + k_gemm_prep re-tiled
// 128x128 -> 64x64 (8 -> 32 blocks; the 8-block launch left 248 CUs idle on
// a serial dispatch). Identical K-order -> bit-identical compose output.
#define TT 8192
#define BB 8
#define DD 256
#define NTOK (BB * TT)

typedef unsigned short u16;
typedef unsigned int u32;

typedef __attribute__((ext_vector_type(8))) short bf16x8;
typedef __attribute__((ext_vector_type(4))) float f32x4;

__device__ __forceinline__ float bf2f(u16 u) {
    u32 v = ((u32)u) << 16;
    float f;
    __builtin_memcpy(&f, &v, 4);
    return f;
}

__device__ __forceinline__ u16 f2bf(float f) {
    u32 v;
    __builtin_memcpy(&v, &f, 4);
    u32 r = (v + 0x7FFFu + ((v >> 16) & 1u)) >> 16;  // RNE
    return (u16)r;
}

__device__ __forceinline__ uint2 pack4(const float* v) {
    uint2 p;
    p.x = (u32)f2bf(v[0]) | ((u32)f2bf(v[1]) << 16);
    p.y = (u32)f2bf(v[2]) | ((u32)f2bf(v[3]) << 16);
    return p;
}

__device__ __forceinline__ void unpack4(uint2 p, float* v) {
    v[0] = bf2f((u16)(p.x & 0xFFFFu));
    v[1] = bf2f((u16)(p.x >> 16));
    v[2] = bf2f((u16)(p.y & 0xFFFFu));
    v[3] = bf2f((u16)(p.y >> 16));
}

__device__ __forceinline__ uint4 pack8(const float* v) {
    uint4 p;
    p.x = (u32)f2bf(v[0]) | ((u32)f2bf(v[1]) << 16);
    p.y = (u32)f2bf(v[2]) | ((u32)f2bf(v[3]) << 16);
    p.z = (u32)f2bf(v[4]) | ((u32)f2bf(v[5]) << 16);
    p.w = (u32)f2bf(v[6]) | ((u32)f2bf(v[7]) << 16);
    return p;
}

__device__ __forceinline__ void unpack8(uint4 p, float* v) {
    v[0] = bf2f((u16)(p.x & 0xFFFFu));
    v[1] = bf2f((u16)(p.x >> 16));
    v[2] = bf2f((u16)(p.y & 0xFFFFu));
    v[3] = bf2f((u16)(p.y >> 16));
    v[4] = bf2f((u16)(p.z & 0xFFFFu));
    v[5] = bf2f((u16)(p.z >> 16));
    v[6] = bf2f((u16)(p.w & 0xFFFFu));
    v[7] = bf2f((u16)(p.w >> 16));
}

// ---------------------------------------------------------------------------
__global__ __launch_bounds__(256) void k_diag(float* out, float code) {
    out[(size_t)blockIdx.x * 256 + threadIdx.x] = code;
}

// ---------------------------------------------------------------------------
// Weight transpose/convert fp32 -> bf16 (proven) + bias compose folded in
// (z=6,7).
// ---------------------------------------------------------------------------
__global__ __launch_bounds__(256) void k_transpose(
    const float* s0, const float* s1, const float* s2, const float* s3,
    const float* s4, const float* s5,
    u16* d0, u16* d1, u16* d2, u16* d3, u16* d4, u16* d5,
    const float* tbv, const float* tbo, const float* abv, const float* abo,
    float* bc1, float* bc2) {
    const int z = blockIdx.z;
    if (z >= 6) {  // bias compose: bc[n] = sum_j bv[j]*Wo[j][n] + bo[n]
        if (blockIdx.x || blockIdx.y) return;
        const float* bv = (z == 7) ? abv : tbv;
        const float* Wo = (z == 7) ? s1 : s0;  // aWo : tWo (fp32 sources)
        const float* bo = (z == 7) ? abo : tbo;
        float* bc = (z == 7) ? bc2 : bc1;
        const int n = threadIdx.x;
        float s = bo[n];
        for (int j = 0; j < 256; j++) s += bv[j] * Wo[j * 256 + n];
        bc[n] = s;
        return;
    }
    const float* src;
    u16* dst;
    int K, N, tr;
    switch (z) {
        case 0: src = s0; dst = d0; K = 256; N = 256; tr = 1; break;
        case 1: src = s1; dst = d1; K = 256; N = 256; tr = 1; break;
        case 2: src = s2; dst = d2; K = 256; N = 512; tr = 1; break;
        case 3: src = s3; dst = d3; K = 512; N = 256; tr = 1; break;
        case 4: src = s4; dst = d4; K = 256; N = 256; tr = 0; break;
        default: src = s5; dst = d5; K = 256; N = 256; tr = 0; break;
    }
    const int nb = blockIdx.x * 32, kb = blockIdx.y * 32;
    if (nb >= N || kb >= K) return;
    const int tx = threadIdx.x & 31, ty = threadIdx.x >> 5;
    if (!tr) {
        for (int i = ty; i < 32; i += 8)
            dst[(size_t)(kb + i) * N + nb + tx] =
                f2bf(src[(size_t)(kb + i) * N + nb + tx]);
        return;
    }
    __shared__ u16 tile[32][33];
    for (int i = ty; i < 32; i += 8)
        tile[i][tx] = f2bf(src[(size_t)(kb + i) * N + nb + tx]);
    __syncthreads();
    for (int i = ty; i < 32; i += 8)
        dst[(size_t)(nb + i) * K + kb + tx] = tile[tx][i];
}

// ---------------------------------------------------------------------------
// Prep-only MFMA GEMM (weight composition, 256x256), both sets in one launch.
// r15: 64x64 tiles, grid (4,4,2) = 32 blocks (was 128x128 / 8 blocks — only
// 8 of 256 CUs busy on this serial dispatch). Per-block: 8 k-steps, 32 MFMA.
// Same ascending-K accumulation order -> bit-identical output.
// ---------------------------------------------------------------------------
__global__ __launch_bounds__(256) void k_gemm_prep(
    const u16* __restrict__ A0, const u16* __restrict__ B0, u16* O0,
    const u16* __restrict__ A1, const u16* __restrict__ B1, u16* O1) {
    const u16* A = blockIdx.z ? A1 : A0;
    const u16* Wt = blockIdx.z ? B1 : B0;
    u16* out = blockIdx.z ? O1 : O0;
    const int m0 = blockIdx.y * 64;
    const int n0 = blockIdx.x * 64;
    const int tid = threadIdx.x;
    const int wv = tid >> 6, lane = tid & 63;
    const int quad = lane >> 4, l16 = lane & 15;
    const int wn = wv * 16;  // wave's 16 output columns

    __shared__ u16 lA[64 * 40];
    __shared__ u16 lB[64 * 40];

    f32x4 acc[4];
#pragma unroll
    for (int i = 0; i < 4; i++) acc[i] = (f32x4){0.f, 0.f, 0.f, 0.f};

    const int r = tid >> 2;  // 0..63
    const int c = tid & 3;   // 0..3

    for (int k0 = 0; k0 < 256; k0 += 32) {
        __syncthreads();
        {
            const uint4 a0 = *(const uint4*)(A + (size_t)(m0 + r) * 256 + k0 + c * 8);
            const uint4 b0 = *(const uint4*)(Wt + (size_t)(n0 + r) * 256 + k0 + c * 8);
            *(uint4*)(lA + r * 40 + c * 8) = a0;
            *(uint4*)(lB + r * 40 + c * 8) = b0;
        }
        __syncthreads();
        bf16x8 bfr = *(const bf16x8*)(lB + (wn + l16) * 40 + quad * 8);
#pragma unroll
        for (int i = 0; i < 4; i++) {
            const bf16x8 af =
                *(const bf16x8*)(lA + (i * 16 + l16) * 40 + quad * 8);
            acc[i] = __builtin_amdgcn_mfma_f32_16x16x32_bf16(af, bfr, acc[i],
                                                             0, 0, 0);
        }
    }

#pragma unroll
    for (int i = 0; i < 4; i++) {
        const int rowb = m0 + i * 16 + quad * 4;
        const int col = n0 + wn + l16;
#pragma unroll
        for (int rr = 0; rr < 4; rr++)
            out[(size_t)(rowb + rr) * 256 + col] = f2bf(acc[i][rr]);
    }
}

// ---------------------------------------------------------------------------
// k_p12: fused P1+P2, 512 threads / 8 waves (r6-proven).
//   r1 = x + temporal(LN1(x))@Wc1 + bc1 -> outf (fp32)
//   h2 = LN2(r1)*g+b -> hout (bf16)
// ---------------------------------------------------------------------------
__global__ __launch_bounds__(512, 4) void k_p12(
    const float* __restrict__ x, const float* __restrict__ n1g,
    const float* __restrict__ n1b, const u16* __restrict__ Wt,
    const float* __restrict__ bias, float* outf,
    const float* __restrict__ lng, const float* __restrict__ lnb,
    u16* __restrict__ hout) {
    const int b = blockIdx.y;
    const int t0 = blockIdx.x * 64;
    const size_t base = (size_t)b * TT;
    const int t = threadIdx.x;
    const int lane = t & 63, wv = t >> 6;
    const int quad = lane >> 4, l16 = lane & 15;
    const int wn = wv * 32;

    __shared__ __attribute__((aligned(16))) u16 hl[79 * 256];   // 40448 B
    __shared__ __attribute__((aligned(16))) u16 sAg[64 * 264];  // 33792 B
    float* sE = (float*)hl;  // epilogue reuse (16 x 268 f32 = 17152 B)
    __shared__ float sMean[16], sRstd[16];
    __shared__ float sG[256], sBl[256];

    if (t < 256) {
        sG[t] = lng[t];
        sBl[t] = lnb[t];
    }

    // ---- Phase A: LN1 rows into hl (proven body; 8 waves stripe rows) ----
    const int d4 = lane * 4;
    {
        const float4 gv = *(const float4*)(n1g + d4);
        const float4 bv = *(const float4*)(n1b + d4);
        for (int i = wv; i < 79; i += 8) {
            const int tt = t0 + i - 15;
            if (tt < 0) {
                *(uint2*)(hl + i * 256 + d4) = make_uint2(0u, 0u);
                continue;
            }
            const float4 v = *(const float4*)(x + (base + tt) * DD + d4);
            float s = v.x + v.y + v.z + v.w;
            float ss = v.x * v.x + v.y * v.y + v.z * v.z + v.w * v.w;
            for (int m = 1; m < 64; m <<= 1) {
                s += __shfl_xor(s, m);
                ss += __shfl_xor(ss, m);
            }
            const float mean = s * (1.0f / 256.0f);
            const float var = ss * (1.0f / 256.0f) - mean * mean;
            const float rs = rsqrtf(fmaxf(var, 0.f) + 1e-5f);
            float h[4] = {(v.x - mean) * rs * gv.x + bv.x,
                          (v.y - mean) * rs * gv.y + bv.y,
                          (v.z - mean) * rs * gv.z + bv.z,
                          (v.w - mean) * rs * gv.w + bv.w};
            *(uint2*)(hl + i * 256 + d4) = pack4(h);
        }
    }
    __syncthreads();

    // ---- Phase B: sliding-window temporal agg -> sAg (8 rows per wave) ----
    {
        float p = 1.f, s = 0.f, w15 = 1.f;
        for (int j = 0; j < 16; j++) {
            s += p;
            if (j == 15) w15 = p;
            p *= 0.9f;
        }
        const float c = 1.f / s;
        const float inv09 = 1.0f / 0.9f;
        const int tg = wv * 8;
        float g[4] = {0.f, 0.f, 0.f, 0.f};
        float pw = 1.f;
        for (int j = 0; j < 16; j++) {
            float h[4];
            unpack4(*(const uint2*)(hl + (tg + j) * 256 + d4), h);
            g[0] += pw * h[0];
            g[1] += pw * h[1];
            g[2] += pw * h[2];
            g[3] += pw * h[3];
            pw *= 0.9f;
        }
        {
            float a[4] = {c * g[0], c * g[1], c * g[2], c * g[3]};
            *(uint2*)(sAg + tg * 264 + d4) = pack4(a);
        }
        for (int ot = tg + 1; ot < tg + 8; ++ot) {
            float hold[4], hnew[4];
            unpack4(*(const uint2*)(hl + (ot - 1) * 256 + d4), hold);
            unpack4(*(const uint2*)(hl + (ot + 15) * 256 + d4), hnew);
#pragma unroll
            for (int e = 0; e < 4; e++)
                g[e] = (g[e] - hold[e]) * inv09 + w15 * hnew[e];
            float a[4] = {c * g[0], c * g[1], c * g[2], c * g[3]};
            *(uint2*)(sAg + ot * 264 + d4) = pack4(a);
        }
    }
    __syncthreads();

    // ---- Phase C: GEMM, barrier-free K-loop; 32 N-cols per wave ----
    f32x4 acc[4][2];
#pragma unroll
    for (int i = 0; i < 4; i++)
#pragma unroll
        for (int j = 0; j < 2; j++) acc[i][j] = (f32x4){0.f, 0.f, 0.f, 0.f};
#pragma unroll
    for (int ks = 0; ks < 8; ks++) {
        bf16x8 bfr[2], af[4];
#pragma unroll
        for (int j = 0; j < 2; j++)
            bfr[j] = *(const bf16x8*)(Wt + (size_t)(wn + j * 16 + l16) * 256 +
                                      ks * 32 + quad * 8);
#pragma unroll
        for (int i = 0; i < 4; i++)
            af[i] = *(const bf16x8*)(sAg + (i * 16 + l16) * 264 + ks * 32 +
                                     quad * 8);
#pragma unroll
        for (int i = 0; i < 4; i++)
#pragma unroll
            for (int j = 0; j < 2; j++)
                acc[i][j] = __builtin_amdgcn_mfma_f32_16x16x32_bf16(
                    af[i], bfr[j], acc[i][j], 0, 0, 0);
    }

    // ---- Phase D: epilogue (res=x, fp32 out, LN2 bf16 out) ----
    float bvl[2];
#pragma unroll
    for (int j = 0; j < 2; j++) bvl[j] = bias[wn + j * 16 + l16];

    const int row = t >> 5;         // 0..15
    const int colb = (t & 31) * 8;  // 0..248
    for (int cch = 0; cch < 4; cch++) {
        const size_t grow = base + t0 + cch * 16 + row;
        __syncthreads();  // guard sE overlay of hl + prior chunk reads
        {
            const float* rp = x + grow * 256 + colb;
            float* sp = sE + row * 268 + colb;
#pragma unroll
            for (int q = 0; q < 2; q++)
                *(float4*)(sp + q * 4) = *(const float4*)(rp + q * 4);
        }
        __syncthreads();
#pragma unroll
        for (int j = 0; j < 2; j++) {
#pragma unroll
            for (int rr = 0; rr < 4; rr++) {
                const int rl = quad * 4 + rr;
                const int ad = rl * 268 + wn + j * 16 + l16;
                sE[ad] += acc[cch][j][rr] + bvl[j];
            }
        }
        __syncthreads();
#pragma unroll
        for (int r4 = 0; r4 < 2; r4++) {
            const int rl = wv * 2 + r4;
            const float4 vv = *(const float4*)(sE + rl * 268 + lane * 4);
            float s = vv.x + vv.y + vv.z + vv.w;
            float ss = vv.x * vv.x + vv.y * vv.y + vv.z * vv.z + vv.w * vv.w;
            for (int m = 1; m < 64; m <<= 1) {
                s += __shfl_xor(s, m);
                ss += __shfl_xor(ss, m);
            }
            if (lane == 0) {
                const float mean = s * (1.0f / 256.0f);
                const float var = ss * (1.0f / 256.0f) - mean * mean;
                sMean[rl] = mean;
                sRstd[rl] = rsqrtf(fmaxf(var, 0.f) + 1e-5f);
            }
        }
        __syncthreads();
        const float* sp = sE + row * 268 + colb;
        {
            float* op = outf + grow * 256 + colb;
#pragma unroll
            for (int q = 0; q < 2; q++)
                *(float4*)(op + q * 4) = *(const float4*)(sp + q * 4);
        }
        {
            const float m = sMean[row], rs = sRstd[row];
            float h[8];
#pragma unroll
            for (int e = 0; e < 8; e++)
                h[e] = (sp[e] - m) * rs * sG[colb + e] + sBl[colb + e];
            u16* hp = hout + grow * 256 + colb;
            *(uint4*)hp = pack8(h);
        }
    }
}

// ---------------------------------------------------------------------------
// k_mega2: P3 (3-tap neighbor GEMM + residual + LN3 out), 512 threads
// (r6-proven exact body, lb(512,4)).
// ---------------------------------------------------------------------------
__global__ __launch_bounds__(512, 4) void k_mega2(
    const u16* __restrict__ A,      // [NTOK][256] bf16 (h2)
    const u16* __restrict__ Wt,     // [256][256] bf16 (N-major)
    const float* __restrict__ bias, // [256] composed
    const float* res,               // [NTOK][256] fp32 (may alias outf)
    float* outf,                    // [NTOK][256] fp32
    const float* __restrict__ lng, const float* __restrict__ lnb,
    u16* __restrict__ hout) {       // [NTOK][256] bf16 LN output
    const int m0 = blockIdx.x * 64;
    const int t = threadIdx.x;
    const int lane = t & 63, wv = t >> 6;
    const int quad = lane >> 4, l16 = lane & 15;
    const int wn = wv * 32;

    __shared__ __attribute__((aligned(16))) u16 sA[8 * 64 * 40];
    float* sE = (float*)sA;  // epilogue reuse: 16 x 268 f32
    __shared__ float sMean[16], sRstd[16];
    __shared__ float sG[256], sBl[256];

    if (t < 256) {
        sG[t] = lng[t];
        sBl[t] = lnb[t];
    }

    // ---- stage A = 3-tap neighbor mean (edge-replicate per batch) ----
#pragma unroll
    for (int q = 0; q < 4; q++) {
        const int id = q * 512 + t;
        const int arow = id >> 5;      // 0..63
        const int c8 = (id & 31) * 8;  // 0..248
        const int ks = c8 >> 5;
        const int kc = c8 & 31;
        const int gr = m0 + arow;
        const int rm = ((gr & (TT - 1)) == 0) ? gr : gr - 1;
        const int rp = (((gr + 1) & (TT - 1)) == 0) ? gr : gr + 1;
        float v0[8], v1[8], v2[8], o[8];
        unpack8(*(const uint4*)(A + (size_t)rm * 256 + c8), v0);
        unpack8(*(const uint4*)(A + (size_t)gr * 256 + c8), v1);
        unpack8(*(const uint4*)(A + (size_t)rp * 256 + c8), v2);
#pragma unroll
        for (int e = 0; e < 8; e++)
            o[e] = (v0[e] + v1[e] + v2[e]) * (1.0f / 3.0f);
        *(uint4*)(sA + (ks * 64 + arow) * 40 + kc) = pack8(o);
    }

    f32x4 acc[4][2];
#pragma unroll
    for (int i = 0; i < 4; i++)
#pragma unroll
        for (int j = 0; j < 2; j++) acc[i][j] = (f32x4){0.f, 0.f, 0.f, 0.f};

    __syncthreads();

    // ---- K-loop: no barriers; B straight from L2; 32 N-cols per wave ----
#pragma unroll
    for (int ks = 0; ks < 8; ks++) {
        bf16x8 bfr[2], af[4];
#pragma unroll
        for (int j = 0; j < 2; j++)
            bfr[j] = *(const bf16x8*)(Wt + (size_t)(wn + j * 16 + l16) * 256 +
                                      ks * 32 + quad * 8);
#pragma unroll
        for (int i = 0; i < 4; i++)
            af[i] = *(const bf16x8*)(sA + (ks * 64 + i * 16 + l16) * 40 +
                                     quad * 8);
#pragma unroll
        for (int i = 0; i < 4; i++)
#pragma unroll
            for (int j = 0; j < 2; j++)
                acc[i][j] = __builtin_amdgcn_mfma_f32_16x16x32_bf16(
                    af[i], bfr[j], acc[i][j], 0, 0, 0);
    }

    // ---- epilogue: res + bias add, fp32 store, LN bf16 store ----
    float bvl[2];
#pragma unroll
    for (int j = 0; j < 2; j++) bvl[j] = bias[wn + j * 16 + l16];

    const int row = t >> 5;         // 0..15
    const int colb = (t & 31) * 8;  // 0..248
    for (int cch = 0; cch < 4; cch++) {
        const int gr = m0 + cch * 16 + row;
        __syncthreads();  // guard sE/sA reuse + prior chunk reads
        {
            const float* rp = res + (size_t)gr * 256 + colb;
            float* sp = sE + row * 268 + colb;
#pragma unroll
            for (int q = 0; q < 2; q++)
                *(float4*)(sp + q * 4) = *(const float4*)(rp + q * 4);
        }
        __syncthreads();
#pragma unroll
        for (int j = 0; j < 2; j++) {
#pragma unroll
            for (int rr = 0; rr < 4; rr++) {
                const int rl = quad * 4 + rr;
                const int ad = rl * 268 + wn + j * 16 + l16;
                sE[ad] += acc[cch][j][rr] + bvl[j];
            }
        }
        __syncthreads();
#pragma unroll
        for (int r4 = 0; r4 < 2; r4++) {
            const int rl = wv * 2 + r4;
            const float4 vv = *(const float4*)(sE + rl * 268 + lane * 4);
            float s = vv.x + vv.y + vv.z + vv.w;
            float ss = vv.x * vv.x + vv.y * vv.y + vv.z * vv.z + vv.w * vv.w;
            for (int m = 1; m < 64; m <<= 1) {
                s += __shfl_xor(s, m);
                ss += __shfl_xor(ss, m);
            }
            if (lane == 0) {
                const float mean = s * (1.0f / 256.0f);
                const float var = ss * (1.0f / 256.0f) - mean * mean;
                sMean[rl] = mean;
                sRstd[rl] = rsqrtf(fmaxf(var, 0.f) + 1e-5f);
            }
        }
        __syncthreads();
        const float* sp = sE + row * 268 + colb;
        {
            float* op = outf + (size_t)gr * 256 + colb;
#pragma unroll
            for (int q = 0; q < 2; q++)
                *(float4*)(op + q * 4) = *(const float4*)(sp + q * 4);
        }
        {
            const float m = sMean[row], rs = sRstd[row];
            float h[8];
#pragma unroll
            for (int e = 0; e < 8; e++)
                h[e] = (sp[e] - m) * rs * sG[colb + e] + sBl[colb + e];
            u16* hp = hout + (size_t)gr * 256 + colb;
            *(uint4*)hp = pack8(h);
        }
    }
}

// ---------------------------------------------------------------------------
// k_ffn: out = res + gelu(A@W1+b1)@W2 + b2, 512 threads / 8 waves
// (r6-proven exact body: sA stride 40, sT 64x136 single-buffer, bw2 prefetch
// after GEMM1, 4x16-row LDS epilogue; lb(512,4), VGPR 56, LDS 58368,
// measured 99.0 µs — empirical floor of this decomposition after six null
// or negative interventions).
// ---------------------------------------------------------------------------
__global__ __launch_bounds__(512, 4) void k_ffn(
    const u16* __restrict__ A,    // [NTOK][256] bf16 (h3)
    const u16* __restrict__ W1T,  // [512][256] bf16
    const float* __restrict__ b1, // [512]
    const u16* __restrict__ W2T,  // [256][512] bf16
    const float* __restrict__ b2, // [256]
    const float* res,             // [NTOK][256] fp32 (r2) — may alias out
    float* out) {
    const int m0 = blockIdx.x * 64;
    const int t = threadIdx.x;
    const int lane = t & 63, wv = t >> 6;
    const int quad = lane >> 4, l16 = lane & 15;
    const int wn = wv * 32;

    __shared__ __attribute__((aligned(16))) u16 sA[8 * 64 * 40];  // 40960 B
    __shared__ __attribute__((aligned(16))) u16 sT[64 * 136];     // 17408 B
    float* sE = (float*)sA;  // epilogue reuse: 16 x 268 f32

    // ---- stage A tile (64 x 256 bf16 = 2048 uint4, coalesced) ----
#pragma unroll
    for (int q = 0; q < 4; q++) {
        const int id = q * 512 + t;
        const int arow = id >> 5;        // 0..63
        const int c8 = (id & 31) * 8;    // 0..248
        const int ks = c8 >> 5;          // 0..7
        const int kc = c8 & 31;          // 0,8,16,24
        *(uint4*)(sA + (ks * 64 + arow) * 40 + kc) =
            *(const uint4*)(A + (size_t)(m0 + arow) * 256 + c8);
    }

    f32x4 acc2[4][2];
#pragma unroll
    for (int i = 0; i < 4; i++)
#pragma unroll
        for (int jj = 0; jj < 2; jj++) acc2[i][jj] = (f32x4){0.f, 0.f, 0.f, 0.f};

    __syncthreads();

    for (int j4 = 0; j4 < 4; j4++) {
        // ---- GEMM1: wave wv computes T1[:, j4*128 + wv*16 .. +15] ----
        const int n1 = j4 * 128 + wv * 16 + l16;
        bf16x8 bw[8];
#pragma unroll
        for (int ks = 0; ks < 8; ks++)
            bw[ks] = *(const bf16x8*)(W1T + (size_t)n1 * 256 + ks * 32 + quad * 8);
        f32x4 acc1[4];
#pragma unroll
        for (int i = 0; i < 4; i++) acc1[i] = (f32x4){0.f, 0.f, 0.f, 0.f};
#pragma unroll
        for (int ks = 0; ks < 8; ks++) {
#pragma unroll
            for (int i = 0; i < 4; i++) {
                const bf16x8 af = *(const bf16x8*)(
                    sA + (ks * 64 + i * 16 + l16) * 40 + quad * 8);
                acc1[i] = __builtin_amdgcn_mfma_f32_16x16x32_bf16(
                    af, bw[ks], acc1[i], 0, 0, 0);
            }
        }
        // ---- prefetch W2 fragments for this chunk (independent of sT) ----
        bf16x8 bw2[8];
#pragma unroll
        for (int kh = 0; kh < 4; kh++)
#pragma unroll
            for (int jj = 0; jj < 2; jj++)
                bw2[kh * 2 + jj] = *(const bf16x8*)(
                    W2T + (size_t)(wn + jj * 16 + l16) * 512 + j4 * 128 +
                    kh * 32 + quad * 8);
        // ---- bias + exact GELU, pack to sT (row quad*4+rr, col wv*16+l16) --
        const float b1l = b1[n1];
#pragma unroll
        for (int i = 0; i < 4; i++)
#pragma unroll
            for (int rr = 0; rr < 4; rr++) {
                float v = acc1[i][rr] + b1l;
                v = 0.5f * v * (1.0f + erff(v * 0.70710678118654752f));
                sT[(i * 16 + quad * 4 + rr) * 136 + wv * 16 + l16] = f2bf(v);
            }
        __syncthreads();
        // ---- GEMM2: acc2 += T1chunk @ W2[j4*128 .. +127][:] ----
#pragma unroll
        for (int kh = 0; kh < 4; kh++) {
#pragma unroll
            for (int i = 0; i < 4; i++) {
                const bf16x8 af = *(const bf16x8*)(
                    sT + (i * 16 + l16) * 136 + kh * 32 + quad * 8);
#pragma unroll
                for (int jj = 0; jj < 2; jj++)
                    acc2[i][jj] = __builtin_amdgcn_mfma_f32_16x16x32_bf16(
                        af, bw2[kh * 2 + jj], acc2[i][jj], 0, 0, 0);
            }
        }
        __syncthreads();  // sT (and, after j4=3, sA) free for reuse
    }

    // ---- epilogue: out = acc2 + b2 + res, fp32, 4 chunks of 16 rows ----
    float bvl[2];
#pragma unroll
    for (int jj = 0; jj < 2; jj++) bvl[jj] = b2[wn + jj * 16 + l16];
    const int row = t >> 5;         // 0..15
    const int colb = (t & 31) * 8;  // 0..248
    for (int cch = 0; cch < 4; cch++) {
        const int gr = m0 + cch * 16 + row;
        __syncthreads();
        {
            const float* rp = res + (size_t)gr * 256 + colb;
            float* sp = sE + row * 268 + colb;
#pragma unroll
            for (int q = 0; q < 2; q++)
                *(float4*)(sp + q * 4) = *(const float4*)(rp + q * 4);
        }
        __syncthreads();
#pragma unroll
        for (int jj = 0; jj < 2; jj++)
#pragma unroll
            for (int rr = 0; rr < 4; rr++) {
                const int ad = (quad * 4 + rr) * 268 + wn + jj * 16 + l16;
                sE[ad] += acc2[cch][jj][rr] + bvl[jj];
            }
        __syncthreads();
        {
            float* op = out + (size_t)gr * 256 + colb;
            const float* sp = sE + row * 268 + colb;
#pragma unroll
            for (int q = 0; q < 2; q++)
                *(float4*)(op + q * 4) = *(const float4*)(sp + q * 4);
        }
    }
}

// ---------------------------------------------------------------------------
extern "C" void kernel_launch(void* const* d_in, const int* in_sizes, int n_in,
                              void* d_out, int out_size, void* d_ws,
                              size_t ws_size, hipStream_t stream) {
    const float* x = (const float*)d_in[0];
    const float* n1g = (const float*)d_in[1];
    const float* n1b = (const float*)d_in[2];
    const float* n2g = (const float*)d_in[3];
    const float* n2b = (const float*)d_in[4];
    const float* n3g = (const float*)d_in[5];
    const float* n3b = (const float*)d_in[6];
    const float* tWv = (const float*)d_in[7];
    const float* tbv = (const float*)d_in[8];
    const float* tWo = (const float*)d_in[9];
    const float* tbo = (const float*)d_in[10];
    const float* aWv = (const float*)d_in[11];
    const float* abv = (const float*)d_in[12];
    const float* aWo = (const float*)d_in[13];
    const float* abo = (const float*)d_in[14];
    const float* fW1 = (const float*)d_in[15];
    const float* fb1 = (const float*)d_in[16];
    const float* fW2 = (const float*)d_in[17];
    const float* fb2 = (const float*)d_in[18];
    float* outp = (float*)d_out;

    u16* wq = (u16*)d_ws;
    u16* tWoT = wq;                      //  65536  [256][256]
    u16* aWoT = wq + 65536;              //  65536
    u16* fW1T = wq + 131072;             // 131072  [512][256]
    u16* fW2T = wq + 262144;             // 131072  [256][512]
    u16* WcT1 = wq + 393216;             //  65536
    u16* WcT2 = wq + 458752;             //  65536
    u16* tWvB = wq + 524288;             //  65536
    u16* aWvB = wq + 589824;             //  65536
    float* bc1 = (float*)(wq + 655360);  //  256 fp32
    float* bc2 = (float*)(wq + 655872);  //  256 fp32
    const size_t W_ELEMS = 656384;
    const size_t SLOT = (size_t)NTOK * 256;
    u16* slot1 = wq + W_ELEMS;
    u16* slot2 = slot1 + SLOT;

    const size_t need = (W_ELEMS + 3 * SLOT) * 2;  // ~97.3 MB (fits: r5)
    if (ws_size < need) {
        k_diag<<<dim3(NTOK), 256, 0, stream>>>(outp,
                                               512.0f + (float)(ws_size >> 20));
        return;
    }

    // --- weight prep (2 launches) ---
    k_transpose<<<dim3(16, 16, 8), 256, 0, stream>>>(
        tWo, aWo, fW1, fW2, tWv, aWv, tWoT, aWoT, fW1T, fW2T, tWvB, aWvB,
        tbv, tbo, abv, abo, bc1, bc2);
    k_gemm_prep<<<dim3(4, 4, 2), 256, 0, stream>>>(tWoT, tWvB, WcT1, aWoT,
                                                   aWvB, WcT2);

    // P1+P2 fused: r1 = x + temporal(LN1(x))@Wc1 + bc1 -> d_out (fp32);
    //              h2 = LN2(r1) -> slot2 (bf16)
    k_p12<<<dim3(TT / 64, BB), 512, 0, stream>>>(x, n1g, n1b, WcT1, bc1, outp,
                                                 n2g, n2b, slot2);

    // P3: r2 = r1 + nbr(h2)@Wc2 + bc2 -> d_out (in-place); h3 = LN3 -> slot1
    k_mega2<<<dim3(NTOK / 64), 512, 0, stream>>>(slot2, WcT2, bc2, outp, outp,
                                                 n3g, n3b, slot1);

    // P4+P5+P6 fused: out = r2 + gelu(h3@W1+b1)@W2 + b2 (in-place residual)
    k_ffn<<<dim3(NTOK / 64), 512, 0, stream>>>(slot1, fW1T, fb1, fW2T, fb2,
                                               outp, outp);
}